// Round 6
// baseline (750.034 us; speedup 1.0000x reference)
//
#include <hip/hip_runtime.h>
#include <hip/hip_cooperative_groups.h>

namespace cg = cooperative_groups;

#define NB 32      // batches
#define MM 448
#define CC 384
#define SS 512
#define KNN 8
#define NBLK 512   // cooperative grid: 2 blocks/CU * 256 CUs

// workspace byte offsets
#define WS_IDX   0u
#define WS_H1    524288u                 // int idx[32][512][8] before this
#define WS_PMAX  (WS_H1 + 4194304u)      // float h1[32][512][64]
#define WS_Q     (WS_PMAX + 262144u)     // float pmax[512][128]
#define WS_Y     (WS_Q + 49152u)         // float y[32][1024]
#define WS_G2    (WS_Y + 131072u)        // float g2[32][1024]
#define WS_BASEP (WS_G2 + 131072u)       // float basep[32][384]
#define WS_PP    WS_H1                   // pp[44][32][384] reuses h1 (dead after gc2)
#define WS_KV    WS_IDX                  // kv/vv reuse idx region (dead after gc2)
#define WS_VV    (WS_IDX + 49152u)

struct P {
  const float *coarse, *skel, *g1wr, *g1wl, *g1b, *g2wr, *g2wl, *g2b,
              *projw, *projb, *aiw, *aib, *aow, *aob, *i1w, *i1b,
              *bng, *bnb, *bnm, *bnv, *i2w, *i2b, *redw, *redb;
  int* idx_ws;
  float *h1_ws, *pmax, *q_ws, *y_ws, *g2_ws, *basep, *pp, *kv_ws, *vv_ws, *out;
};

__device__ __forceinline__ float wave_sum(float v) {
#pragma unroll
  for (int m = 1; m < 64; m <<= 1) v += __shfl_xor(v, m, 64);
  return v;
}

// One cooperative kernel; stages separated by grid.sync() (replaces 9 launch gaps).
__global__ __launch_bounds__(256, 2) void k_all(P p) {
  cg::grid_group grid = cg::this_grid();
  __shared__ __align__(16) float smem[9600];   // 38.4 KB union of all stages
  const int tid = threadIdx.x;
  const int bid = blockIdx.x;

  // ================= S1: KNN + gc1, wave-per-point (4096 virtual blocks) =====
  {
    float4* sk = (float4*)smem;
    for (int vb = bid; vb < 4096; vb += NBLK) {
      int b = vb >> 7, grp = vb & 127;
      __syncthreads();                       // prior iter's readers done
      const float* sb = p.skel + b * SS * 3;
      for (int t = tid; t < SS; t += 256)
        sk[t] = make_float4(sb[t*3+0], sb[t*3+1], sb[t*3+2], 0.f);
      __syncthreads();

      int wave = tid >> 6, lane = tid & 63;
      int i = grp * 4 + wave;
      float4 pi = sk[i];
      float bd[KNN];
#pragma unroll
      for (int t = 0; t < KNN; t++) {
        int j = lane + (t << 6);
        float4 q = sk[j];
        float d2;
        {
          // match reference arithmetic: (dx^2+dy^2)+dz^2, no fma contraction
#pragma clang fp contract(off)
          float dx = pi.x - q.x, dy = pi.y - q.y, dz = pi.z - q.z;
          d2 = (dx*dx + dy*dy) + dz*dz;
        }
        bd[t] = (j == i) ? 3e38f : d2;
      }
      int win[KNN];
      int* idx_base = p.idx_ws + (size_t)(b*SS + i) * KNN;
#pragma unroll
      for (int t = 0; t < KNN; t++) {
        float bestd = bd[0]; int bests = 0;
#pragma unroll
        for (int s = 1; s < KNN; s++)
          if (bd[s] < bestd) { bestd = bd[s]; bests = s; }
        int bestj = lane + (bests << 6);
#pragma unroll
        for (int m = 1; m < 64; m <<= 1) {
          float od = __shfl_xor(bestd, m, 64);
          int   oj = __shfl_xor(bestj, m, 64);
          if (od < bestd || (od == bestd && oj < bestj)) { bestd = od; bestj = oj; }
        }
        win[t] = bestj;
        if (lane == t) idx_base[t] = bestj;
        if ((bestj & 63) == lane) {
          int sl = bestj >> 6;
#pragma unroll
          for (int s = 0; s < KNN; s++) if (s == sl) bd[s] = 3e38f;
        }
      }
      float a0 = 0.f, a1 = 0.f, a2 = 0.f;
#pragma unroll
      for (int t = 0; t < KNN; t++) {
        float4 n = sk[win[t]];
        a0 += n.x; a1 += n.y; a2 += n.z;
      }
      int c = lane;
      float h = p.g1b[c] + pi.x*p.g1wr[c] + pi.y*p.g1wr[64+c] + pi.z*p.g1wr[128+c]
                         + a0*p.g1wl[c]   + a1*p.g1wl[64+c]   + a2*p.g1wl[128+c];
      p.h1_ws[(size_t)(b*SS + i) * 64 + lane] = fmaxf(h, 0.f);
    }
  }
  grid.sync();

  // ================= S2: gc2+max GEMM [16384x128]@[128x128] (512 blocks 1:1) ==
  {
    float* X    = smem;                  // 32*129
    float* Wt   = smem + 4128;           // 32*128
    float* mred = smem + 8224;           // 8*128
    int*   nbs  = (int*)(smem + 9248);   // 256
    int b = bid >> 4, chunk = bid & 15;
    int r0 = chunk * 32;
    const float* h1b = p.h1_ws + (size_t)b * SS * 64;
    nbs[tid] = p.idx_ws[(b*SS + r0)*KNN + tid];
#pragma unroll
    for (int q = 0; q < 8; q++) {
      int idx = tid + 256*q;
      int r = idx >> 6, k = idx & 63;
      X[r*129 + k] = h1b[(r0 + r)*64 + k];
    }
    __syncthreads();
#pragma unroll
    for (int q = 0; q < 8; q++) {
      int idx = tid + 256*q;
      int r = idx >> 6, k = idx & 63;
      const int* nb = nbs + r*KNN;
      float s = 0.f;
#pragma unroll
      for (int j = 0; j < KNN; j++) s += h1b[nb[j]*64 + k];
      X[r*129 + 64 + k] = s;
    }
    int rg = tid >> 5, cgi = tid & 31;
    float acc[4][4];
#pragma unroll
    for (int r = 0; r < 4; r++)
#pragma unroll
      for (int u = 0; u < 4; u++) acc[r][u] = 0.f;
    const float* wsrc[4] = { p.g2wr, p.g2wr + 32*128, p.g2wl, p.g2wl + 32*128 };
#pragma unroll 1
    for (int ch = 0; ch < 4; ch++) {
      __syncthreads();
      const float* ws = wsrc[ch];
#pragma unroll
      for (int q = 0; q < 16; q++) {
        int idx = tid + 256*q;
        Wt[idx] = ws[idx];
      }
      __syncthreads();
      int kb = ch * 32;
      const float* xr0 = X + (rg*4+0)*129 + kb;
      const float* xr1 = X + (rg*4+1)*129 + kb;
      const float* xr2 = X + (rg*4+2)*129 + kb;
      const float* xr3 = X + (rg*4+3)*129 + kb;
#pragma unroll 4
      for (int k = 0; k < 32; k++) {
        float4 w4 = *(const float4*)(Wt + k*128 + cgi*4);
        float x0 = xr0[k], x1 = xr1[k], x2 = xr2[k], x3 = xr3[k];
        acc[0][0] += x0*w4.x; acc[0][1] += x0*w4.y; acc[0][2] += x0*w4.z; acc[0][3] += x0*w4.w;
        acc[1][0] += x1*w4.x; acc[1][1] += x1*w4.y; acc[1][2] += x1*w4.z; acc[1][3] += x1*w4.w;
        acc[2][0] += x2*w4.x; acc[2][1] += x2*w4.y; acc[2][2] += x2*w4.z; acc[2][3] += x2*w4.w;
        acc[3][0] += x3*w4.x; acc[3][1] += x3*w4.y; acc[3][2] += x3*w4.z; acc[3][3] += x3*w4.w;
      }
    }
#pragma unroll
    for (int u = 0; u < 4; u++)
      mred[rg*128 + cgi*4 + u] =
        fmaxf(fmaxf(acc[0][u], acc[1][u]), fmaxf(acc[2][u], acc[3][u]));
    __syncthreads();
    if (tid < 128) {
      int col = tid;
      float mx = mred[col];
#pragma unroll
      for (int g = 1; g < 8; g++) mx = fmaxf(mx, mred[g*128 + col]);
      p.pmax[(size_t)(b*16 + chunk)*128 + col] = mx + p.g2b[col];
    }
  }
  grid.sync();

  // ================= S3: proxy max + kv (32 virtual blocks) ==================
  if (bid < NB) {
    float* proxy = smem;
    int b = bid;
    if (tid < 128) {
      float m = -3e38f;
      for (int ch = 0; ch < 16; ch++)
        m = fmaxf(m, p.pmax[(size_t)(b*16 + ch)*128 + tid]);
      proxy[tid] = m;
    }
    __syncthreads();
    for (int c = tid; c < CC; c += 256) {
      float acc = p.projb[c];
      for (int s = 0; s < 128; s++) acc += proxy[s] * p.projw[s*CC + c];
      p.kv_ws[b*CC + c] = acc;
    }
  }
  grid.sync();

  // ================= S4: vv = kv @ wv.T + bv (384 virtual blocks) ============
  if (bid < 384) {
    float* xs = smem;
    int b = bid & 31, og = bid >> 5;
    int wv = tid >> 6, lane = tid & 63;
    for (int t = tid; t < CC; t += 256) xs[t] = p.kv_ws[b*CC + t];
    __syncthreads();
    float x0 = xs[lane*6+0], x1 = xs[lane*6+1], x2 = xs[lane*6+2];
    float x3 = xs[lane*6+3], x4 = xs[lane*6+4], x5 = xs[lane*6+5];
#pragma unroll
    for (int u = 0; u < 8; u++) {
      int o = og*32 + wv*8 + u;
      const float* wr = p.aiw + (size_t)(2*CC + o) * CC + lane*6;
      float2 wa = *(const float2*)wr;
      float2 wb = *(const float2*)(wr + 2);
      float2 wc = *(const float2*)(wr + 4);
      float pr = wa.x*x0 + wa.y*x1 + wb.x*x2 + wb.y*x3 + wc.x*x4 + wc.y*x5;
      pr = wave_sum(pr);
      if (lane == 0) p.vv_ws[b*CC + o] = p.aib[2*CC + o] + pr;
    }
  }
  grid.sync();

  // ================= S5: q = vv @ attn_out_w.T + b (384 virtual blocks) ======
  if (bid < 384) {
    float* xs = smem;
    int b = bid & 31, og = bid >> 5;
    int wv = tid >> 6, lane = tid & 63;
    for (int t = tid; t < CC; t += 256) xs[t] = p.vv_ws[b*CC + t];
    __syncthreads();
    float x0 = xs[lane*6+0], x1 = xs[lane*6+1], x2 = xs[lane*6+2];
    float x3 = xs[lane*6+3], x4 = xs[lane*6+4], x5 = xs[lane*6+5];
#pragma unroll
    for (int u = 0; u < 8; u++) {
      int o = og*32 + wv*8 + u;
      const float* wr = p.aow + (size_t)o * CC + lane*6;
      float2 wa = *(const float2*)wr;
      float2 wb = *(const float2*)(wr + 2);
      float2 wc = *(const float2*)(wr + 4);
      float pr = wa.x*x0 + wa.y*x1 + wb.x*x2 + wb.y*x3 + wc.x*x4 + wc.y*x5;
      pr = wave_sum(pr);
      if (lane == 0) p.q_ws[b*CC + o] = p.aob[o] + pr;
    }
  }
  grid.sync();

  // ================= S6: inc1 + BN + leaky (512 blocks 1:1) ==================
  {
    float* xs = smem;
    int b = bid >> 4, og = bid & 15;
    int o = og*64 + (tid >> 2), qq = tid & 3;
    for (int i = tid; i < CC; i += 256) xs[i] = p.q_ws[b*CC + i];
    __syncthreads();
    const float* wr = p.i1w + (size_t)o * CC + qq*96;
    const float* xr = xs + qq*96;
    float acc = 0.f;
#pragma unroll
    for (int kk = 0; kk < 96; kk += 4) {
      float4 w4 = *(const float4*)(wr + kk);
      float4 x4 = *(const float4*)(xr + kk);
      acc += w4.x*x4.x + w4.y*x4.y + w4.z*x4.z + w4.w*x4.w;
    }
    acc += __shfl_xor(acc, 1, 64);
    acc += __shfl_xor(acc, 2, 64);
    if (qq == 0) {
      float a = acc + p.i1b[o];
      float z = p.bng[o] * (a - p.bnm[o]) * rsqrtf(p.bnv[o] + 1e-5f) + p.bnb[o];
      p.y_ws[b*1024 + o] = (z >= 0.f) ? z : 0.2f * z;
    }
  }
  grid.sync();

  // ================= S7: inc2 (512 blocks 1:1) ===============================
  {
    float* xs = smem;
    int b = bid >> 4, og = bid & 15;
    int o = og*64 + (tid >> 2), qq = tid & 3;
    for (int i = tid; i < 1024; i += 256) xs[i] = p.y_ws[b*1024 + i];
    __syncthreads();
    const float* wr = p.i2w + (size_t)o * 1024 + qq*256;
    const float* xr = xs + qq*256;
    float acc = 0.f;
#pragma unroll 8
    for (int kk = 0; kk < 256; kk += 4) {
      float4 w4 = *(const float4*)(wr + kk);
      float4 x4 = *(const float4*)(xr + kk);
      acc += w4.x*x4.x + w4.y*x4.y + w4.z*x4.z + w4.w*x4.w;
    }
    acc += __shfl_xor(acc, 1, 64);
    acc += __shfl_xor(acc, 2, 64);
    if (qq == 0) p.g2_ws[b*1024 + o] = acc + p.i2b[o];
  }
  grid.sync();

  // ================= S8: base partial GEMM (264 virtual blocks) ==============
  if (bid < 264) {
    float* xs = smem;            // 32*33
    float* wt = smem + 1056;     // 32*64
    int cg = bid % 44, o0 = (bid / 44) * 64;
    int c0 = cg * 32;
#pragma unroll
    for (int q = 0; q < 8; q++) {
      int idx = tid + 256*q;
      int c = idx >> 6, o = idx & 63;
      wt[idx] = p.redw[(size_t)(c0 + c)*CC + o0 + o];
    }
    {
      int b = tid >> 3, cp = tid & 7;
      const float* src = (cg < 32) ? (p.g2_ws + b*1024 + c0)
                                   : (p.q_ws  + b*CC   + (c0 - 1024));
      float4 v = *(const float4*)(src + cp*4);
      xs[(cp*4+0)*33 + b] = v.x;
      xs[(cp*4+1)*33 + b] = v.y;
      xs[(cp*4+2)*33 + b] = v.z;
      xs[(cp*4+3)*33 + b] = v.w;
    }
    __syncthreads();
    int b = tid >> 3, og = tid & 7;
    float acc[8];
#pragma unroll
    for (int u = 0; u < 8; u++) acc[u] = 0.f;
#pragma unroll 8
    for (int c = 0; c < 32; c++) {
      float xv = xs[c*33 + b];
      float4 w0 = *(const float4*)(wt + c*64 + og*8);
      float4 w1 = *(const float4*)(wt + c*64 + og*8 + 4);
      acc[0] += xv*w0.x; acc[1] += xv*w0.y; acc[2] += xv*w0.z; acc[3] += xv*w0.w;
      acc[4] += xv*w1.x; acc[5] += xv*w1.y; acc[6] += xv*w1.z; acc[7] += xv*w1.w;
    }
    float* dst = p.pp + (size_t)(cg*32 + b)*CC + o0 + og*8;
    *(float4*)dst       = make_float4(acc[0], acc[1], acc[2], acc[3]);
    *(float4*)(dst + 4) = make_float4(acc[4], acc[5], acc[6], acc[7]);
  }
  grid.sync();

  // ================= S9: reduce 44 partials -> basep (48 virtual blocks) =====
  if (bid < 48) {
    int idx = bid * 256 + tid;   // < 12288
    float s = 0.f;
#pragma unroll 4
    for (int cg = 0; cg < 44; cg++) s += p.pp[cg*12288 + idx];
    p.basep[idx] = s;
  }
  grid.sync();

  // ================= S10: out = base + coarse @ red_w3 (grid-stride) =========
  {
    for (int gid = bid * 256 + tid; gid < 32*448*96; gid += NBLK*256) {
      int c4 = gid % 96;
      int row = gid / 96;
      int b = row / 448;
      int c = c4 * 4;
      float4 p0 = *(const float4*)(p.basep + b*CC + c);
      float4 rb = *(const float4*)(p.redb + c);
      const float* cr = p.coarse + (size_t)row * 3;
      float cx = cr[0], cy = cr[1], cz = cr[2];
      float4 w0 = *(const float4*)(p.redw + (size_t)1408*CC + c);
      float4 w1 = *(const float4*)(p.redw + (size_t)1409*CC + c);
      float4 w2 = *(const float4*)(p.redw + (size_t)1410*CC + c);
      float4 o4;
      o4.x = p0.x + rb.x + cx*w0.x + cy*w1.x + cz*w2.x;
      o4.y = p0.y + rb.y + cx*w0.y + cy*w1.y + cz*w2.y;
      o4.z = p0.z + rb.z + cx*w0.z + cy*w1.z + cz*w2.z;
      o4.w = p0.w + rb.w + cx*w0.w + cy*w1.w + cz*w2.w;
      *(float4*)(p.out + (size_t)row*CC + c) = o4;
    }
  }
}

extern "C" void kernel_launch(void* const* d_in, const int* in_sizes, int n_in,
                              void* d_out, int out_size, void* d_ws, size_t ws_size,
                              hipStream_t stream)
{
  (void)in_sizes; (void)n_in; (void)out_size; (void)ws_size;
  char* ws = (char*)d_ws;
  P prm;
  // d_in[0] is q (B,M,C): provably unused — attention softmax is uniform.
  prm.coarse = (const float*)d_in[1];
  prm.skel   = (const float*)d_in[2];
  prm.g1wr   = (const float*)d_in[3];
  prm.g1wl   = (const float*)d_in[4];
  prm.g1b    = (const float*)d_in[5];
  prm.g2wr   = (const float*)d_in[6];
  prm.g2wl   = (const float*)d_in[7];
  prm.g2b    = (const float*)d_in[8];
  prm.projw  = (const float*)d_in[9];
  prm.projb  = (const float*)d_in[10];
  prm.aiw    = (const float*)d_in[11];
  prm.aib    = (const float*)d_in[12];
  prm.aow    = (const float*)d_in[13];
  prm.aob    = (const float*)d_in[14];
  prm.i1w    = (const float*)d_in[15];
  prm.i1b    = (const float*)d_in[16];
  prm.bng    = (const float*)d_in[17];
  prm.bnb    = (const float*)d_in[18];
  prm.bnm    = (const float*)d_in[19];
  prm.bnv    = (const float*)d_in[20];
  prm.i2w    = (const float*)d_in[21];
  prm.i2b    = (const float*)d_in[22];
  prm.redw   = (const float*)d_in[23];
  prm.redb   = (const float*)d_in[24];
  prm.idx_ws = (int*)(ws + WS_IDX);
  prm.h1_ws  = (float*)(ws + WS_H1);
  prm.pmax   = (float*)(ws + WS_PMAX);
  prm.q_ws   = (float*)(ws + WS_Q);
  prm.y_ws   = (float*)(ws + WS_Y);
  prm.g2_ws  = (float*)(ws + WS_G2);
  prm.basep  = (float*)(ws + WS_BASEP);
  prm.pp     = (float*)(ws + WS_PP);
  prm.kv_ws  = (float*)(ws + WS_KV);
  prm.vv_ws  = (float*)(ws + WS_VV);
  prm.out    = (float*)d_out;

  void* args[] = { &prm };
  hipLaunchCooperativeKernel((const void*)k_all, dim3(NBLK), dim3(256),
                             args, 0, stream);
}

// Round 7
// 284.213 us; speedup vs baseline: 2.6390x; 2.6390x over previous
//
#include <hip/hip_runtime.h>

#define NB 32      // batches
#define MM 448
#define CC 384
#define SS 512
#define KNN 8

// workspace byte offsets
#define WS_IDX   0u
#define WS_H1    524288u                 // int idx[32][512][8] before this
#define WS_PMAX  (WS_H1 + 4194304u)      // float h1[32][512][64]
#define WS_Q     (WS_PMAX + 262144u)     // float pmax[512][128]
#define WS_Y     (WS_Q + 49152u)         // float y[32][1024]
#define WS_G2    (WS_Y + 131072u)        // float g2[32][1024]
#define WS_BASEP (WS_G2 + 131072u)       // float basep[32][384]

// ------------------------------------------------- K1: KNN + gc1, wave-per-point
__global__ __launch_bounds__(256) void k_knn_gc1(
    const float* __restrict__ skel,
    const float* __restrict__ w1root, const float* __restrict__ w1rel,
    const float* __restrict__ b1,
    int* __restrict__ idx_ws, float* __restrict__ h1_ws)
{
  int b   = blockIdx.x >> 7;          // 128 groups of 4 points per batch
  int grp = blockIdx.x & 127;
  __shared__ __align__(16) float4 sk[SS];
  const float* sb = skel + b * SS * 3;
  for (int t = threadIdx.x; t < SS; t += 256)
    sk[t] = make_float4(sb[t*3+0], sb[t*3+1], sb[t*3+2], 0.f);
  __syncthreads();

  int wave = threadIdx.x >> 6, lane = threadIdx.x & 63;
  int i = grp * 4 + wave;             // this wave's point
  float4 pi = sk[i];

  float bd[KNN];
#pragma unroll
  for (int t = 0; t < KNN; t++) {
    int j = lane + (t << 6);
    float4 p = sk[j];
    float d2;
    {
      // match reference arithmetic exactly: (dx^2+dy^2)+dz^2, no fma contraction
#pragma clang fp contract(off)
      float dx = pi.x - p.x, dy = pi.y - p.y, dz = pi.z - p.z;
      d2 = (dx*dx + dy*dy) + dz*dz;
    }
    bd[t] = (j == i) ? 3e38f : d2;
  }

  int win[KNN];
  int* idx_base = idx_ws + (size_t)(b*SS + i) * KNN;
#pragma unroll
  for (int t = 0; t < KNN; t++) {
    float bestd = bd[0]; int bests = 0;
#pragma unroll
    for (int s = 1; s < KNN; s++)
      if (bd[s] < bestd) { bestd = bd[s]; bests = s; }
    int bestj = lane + (bests << 6);
#pragma unroll
    for (int m = 1; m < 64; m <<= 1) {
      float od = __shfl_xor(bestd, m, 64);
      int   oj = __shfl_xor(bestj, m, 64);
      if (od < bestd || (od == bestd && oj < bestj)) { bestd = od; bestj = oj; }
    }
    win[t] = bestj;
    if (lane == t) idx_base[t] = bestj;
    if ((bestj & 63) == lane) {
      int sl = bestj >> 6;
#pragma unroll
      for (int s = 0; s < KNN; s++) if (s == sl) bd[s] = 3e38f;
    }
  }

  float a0 = 0.f, a1 = 0.f, a2 = 0.f;
#pragma unroll
  for (int t = 0; t < KNN; t++) {
    float4 n = sk[win[t]];
    a0 += n.x; a1 += n.y; a2 += n.z;
  }

  int c = lane;
  float h = b1[c] + pi.x*w1root[c] + pi.y*w1root[64+c] + pi.z*w1root[128+c]
                  + a0*w1rel[c]   + a1*w1rel[64+c]   + a2*w1rel[128+c];
  h = fmaxf(h, 0.f);
  h1_ws[(size_t)(b*SS + i) * 64 + lane] = h;
}

// -------- K2: gc2+max as one GEMM [16384x128]@[128x128], fused agg-gather + max
__global__ __launch_bounds__(256) void k_gc2_max(
    const float* __restrict__ h1_ws, const int* __restrict__ idx_ws,
    const float* __restrict__ w2root, const float* __restrict__ w2rel,
    const float* __restrict__ b2, float* __restrict__ pmax)
{
  int b = blockIdx.x >> 4, chunk = blockIdx.x & 15;
  int r0 = chunk * 32;
  __shared__ __align__(16) float X[32*129];   // [row][k], stride 129
  __shared__ __align__(16) float Wt[32*128];  // k-chunk of stacked W
  __shared__ float mred[8*128];
  __shared__ int nbs[32*KNN];

  const float* h1b = h1_ws + (size_t)b * SS * 64;
  nbs[threadIdx.x] = idx_ws[(b*SS + r0)*KNN + threadIdx.x];   // 256 = 32*8
#pragma unroll
  for (int p = 0; p < 8; p++) {
    int idx = threadIdx.x + 256*p;
    int r = idx >> 6, k = idx & 63;
    X[r*129 + k] = h1b[(r0 + r)*64 + k];
  }
  __syncthreads();   // nbs ready
#pragma unroll
  for (int p = 0; p < 8; p++) {
    int idx = threadIdx.x + 256*p;
    int r = idx >> 6, k = idx & 63;
    const int* nb = nbs + r*KNN;
    float s = 0.f;
#pragma unroll
    for (int j = 0; j < KNN; j++) s += h1b[nb[j]*64 + k];
    X[r*129 + 64 + k] = s;
  }

  int rg = threadIdx.x >> 5, cg = threadIdx.x & 31;
  float acc[4][4];
#pragma unroll
  for (int r = 0; r < 4; r++)
#pragma unroll
    for (int u = 0; u < 4; u++) acc[r][u] = 0.f;

  const float* wsrc[4] = { w2root, w2root + 32*128, w2rel, w2rel + 32*128 };
#pragma unroll 1
  for (int ch = 0; ch < 4; ch++) {
    __syncthreads();
    const float* ws = wsrc[ch];
#pragma unroll
    for (int p = 0; p < 16; p++) {
      int idx = threadIdx.x + 256*p;
      Wt[idx] = ws[idx];                 // coalesced
    }
    __syncthreads();
    int kb = ch * 32;
    const float* xr0 = X + (rg*4+0)*129 + kb;
    const float* xr1 = X + (rg*4+1)*129 + kb;
    const float* xr2 = X + (rg*4+2)*129 + kb;
    const float* xr3 = X + (rg*4+3)*129 + kb;
#pragma unroll 4
    for (int k = 0; k < 32; k++) {
      float4 w4 = *(const float4*)(Wt + k*128 + cg*4);
      float x0 = xr0[k], x1 = xr1[k], x2 = xr2[k], x3 = xr3[k];
      acc[0][0] += x0*w4.x; acc[0][1] += x0*w4.y; acc[0][2] += x0*w4.z; acc[0][3] += x0*w4.w;
      acc[1][0] += x1*w4.x; acc[1][1] += x1*w4.y; acc[1][2] += x1*w4.z; acc[1][3] += x1*w4.w;
      acc[2][0] += x2*w4.x; acc[2][1] += x2*w4.y; acc[2][2] += x2*w4.z; acc[2][3] += x2*w4.w;
      acc[3][0] += x3*w4.x; acc[3][1] += x3*w4.y; acc[3][2] += x3*w4.z; acc[3][3] += x3*w4.w;
    }
  }
#pragma unroll
  for (int u = 0; u < 4; u++)
    mred[rg*128 + cg*4 + u] =
      fmaxf(fmaxf(acc[0][u], acc[1][u]), fmaxf(acc[2][u], acc[3][u]));
  __syncthreads();
  if (threadIdx.x < 128) {
    int col = threadIdx.x;
    float mx = mred[col];
#pragma unroll
    for (int g = 1; g < 8; g++) mx = fmaxf(mx, mred[g*128 + col]);
    pmax[(size_t)(b*16 + chunk)*128 + col] = mx + b2[col];
  }
}

// ---- K3: fused proxy->kv->vv->q->inc1+BN. 128 blocks (4/batch), chain redundant
// per block in LDS (per-thread row-dots, no wave_sum chains); weights L2-resident.
__global__ __launch_bounds__(256) void k_mid(
    const float* __restrict__ pmax,
    const float* __restrict__ proj_w, const float* __restrict__ proj_b,
    const float* __restrict__ aiw, const float* __restrict__ aib,
    const float* __restrict__ aow, const float* __restrict__ aob,
    const float* __restrict__ i1w, const float* __restrict__ i1b,
    const float* __restrict__ bng, const float* __restrict__ bnb,
    const float* __restrict__ bnm, const float* __restrict__ bnv,
    float* __restrict__ q_ws, float* __restrict__ y_ws)
{
  int b = blockIdx.x >> 2, sl = blockIdx.x & 3;
  int t = threadIdx.x;
  __shared__ __align__(16) float proxy[128];
  __shared__ __align__(16) float kv[CC];
  __shared__ __align__(16) float vv[CC];
  __shared__ __align__(16) float qv[CC];

  if (t < 128) {
    float m = -3e38f;
    for (int ch = 0; ch < 16; ch++)
      m = fmaxf(m, pmax[(size_t)(b*16 + ch)*128 + t]);
    proxy[t] = m;
  }
  __syncthreads();
  // kv = proxy @ proj_w + proj_b  (lane-coalesced over c)
  for (int c = t; c < CC; c += 256) {
    float acc = proj_b[c];
    for (int s = 0; s < 128; s++) acc += proxy[s] * proj_w[s*CC + c];
    kv[c] = acc;
  }
  __syncthreads();
  // vv[o] = aib[2C+o] + dot(kv, aiw row 2C+o)   (per-thread row, float4)
  for (int o = t; o < CC; o += 256) {
    const float* wr = aiw + (size_t)(2*CC + o) * CC;
    float acc = aib[2*CC + o];
#pragma unroll 8
    for (int k = 0; k < CC; k += 4) {
      float4 w4 = *(const float4*)(wr + k);
      float4 x4 = *(const float4*)(kv + k);
      acc += w4.x*x4.x + w4.y*x4.y + w4.z*x4.z + w4.w*x4.w;
    }
    vv[o] = acc;
  }
  __syncthreads();
  // qv[o] = aob[o] + dot(vv, aow row o)
  for (int o = t; o < CC; o += 256) {
    const float* wr = aow + (size_t)o * CC;
    float acc = aob[o];
#pragma unroll 8
    for (int k = 0; k < CC; k += 4) {
      float4 w4 = *(const float4*)(wr + k);
      float4 x4 = *(const float4*)(vv + k);
      acc += w4.x*x4.x + w4.y*x4.y + w4.z*x4.z + w4.w*x4.w;
    }
    qv[o] = acc;
    if (sl == 0) q_ws[b*CC + o] = acc;
  }
  __syncthreads();
  // inc1 + BN + leaky for this block's slice of 256 outputs
  {
    int o = sl*256 + t;
    const float* wr = i1w + (size_t)o * CC;
    float acc = i1b[o];
#pragma unroll 8
    for (int k = 0; k < CC; k += 4) {
      float4 w4 = *(const float4*)(wr + k);
      float4 x4 = *(const float4*)(qv + k);
      acc += w4.x*x4.x + w4.y*x4.y + w4.z*x4.z + w4.w*x4.w;
    }
    float z = bng[o] * (acc - bnm[o]) * rsqrtf(bnv[o] + 1e-5f) + bnb[o];
    y_ws[b*1024 + o] = (z >= 0.f) ? z : 0.2f * z;
  }
}

// ---------------- K4: inc2. 4 lanes per output, contiguous quarter-rows (K=1024).
__global__ __launch_bounds__(256) void k_inc2(
    const float* __restrict__ y_ws, const float* __restrict__ inc2_w,
    const float* __restrict__ inc2_b, float* __restrict__ g2_ws)
{
  int b = blockIdx.x >> 4, og = blockIdx.x & 15;
  int t = threadIdx.x;
  int o = og*64 + (t >> 2), qq = t & 3;
  __shared__ __align__(16) float xs[1024];
  for (int i = t; i < 1024; i += 256) xs[i] = y_ws[b*1024 + i];
  __syncthreads();
  const float* wr = inc2_w + (size_t)o * 1024 + qq*256;
  const float* xr = xs + qq*256;
  float acc = 0.f;
#pragma unroll 8
  for (int kk = 0; kk < 256; kk += 4) {
    float4 w4 = *(const float4*)(wr + kk);
    float4 x4 = *(const float4*)(xr + kk);
    acc += w4.x*x4.x + w4.y*x4.y + w4.z*x4.z + w4.w*x4.w;
  }
  acc += __shfl_xor(acc, 1, 64);
  acc += __shfl_xor(acc, 2, 64);
  if (qq == 0) g2_ws[b*1024 + o] = acc + inc2_b[o];
}

// ------ K5: base, full-K per block: basep[b][o0+0..63] = X[1408] @ W[:,o0:o0+64]
// 192 blocks (32 b x 6 o-chunks); 4 waves split K, LDS cross-wave reduce.
__global__ __launch_bounds__(256) void k_base(
    const float* __restrict__ g2_ws, const float* __restrict__ q_ws,
    const float* __restrict__ red_w, float* __restrict__ basep)
{
  int b = blockIdx.x >> 3;              // /8? no: 6 chunks -> use y-dim instead
  int o0 = (blockIdx.x & 7) * 64;       // unused pattern; replaced below
  // use explicit 2D: gridDim (32, 6)
  b = blockIdx.x;
  o0 = blockIdx.y * 64;
  int wv = threadIdx.x >> 6, lane = threadIdx.x & 63;
  __shared__ __align__(16) float X[1408];
  __shared__ float part[4][64];
  for (int i = threadIdx.x; i < 1408; i += 256)
    X[i] = (i < 1024) ? g2_ws[b*1024 + i] : q_ws[b*CC + (i - 1024)];
  __syncthreads();
  int k0 = wv * 352;
  float acc = 0.f;
  const float* wbase = red_w + o0 + lane;
#pragma unroll 4
  for (int k = 0; k < 352; k++)
    acc += X[k0 + k] * wbase[(size_t)(k0 + k) * CC];
  part[wv][lane] = acc;
  __syncthreads();
  if (threadIdx.x < 64) {
    float s = part[0][lane] + part[1][lane] + part[2][lane] + part[3][lane];
    basep[b*CC + o0 + lane] = s;
  }
}

// --------------------------------------------- K6: out = base + coarse @ red_w3
__global__ __launch_bounds__(256) void k_out(
    const float* __restrict__ basep, const float* __restrict__ red_b,
    const float* __restrict__ red_w, const float* __restrict__ coarse,
    float* __restrict__ out)
{
  int gid = blockIdx.x * 256 + threadIdx.x;   // < 32*448*96 exactly
  int c4 = gid % 96;
  int row = gid / 96;                          // b*448 + m
  int b = row / 448;
  int c = c4 * 4;
  float4 p0 = *(const float4*)(basep + b*CC + c);
  float4 rb = *(const float4*)(red_b + c);
  const float* cr = coarse + (size_t)row * 3;
  float cx = cr[0], cy = cr[1], cz = cr[2];
  float4 w0 = *(const float4*)(red_w + (size_t)1408*CC + c);
  float4 w1 = *(const float4*)(red_w + (size_t)1409*CC + c);
  float4 w2 = *(const float4*)(red_w + (size_t)1410*CC + c);
  float4 o4;
  o4.x = p0.x + rb.x + cx*w0.x + cy*w1.x + cz*w2.x;
  o4.y = p0.y + rb.y + cx*w0.y + cy*w1.y + cz*w2.y;
  o4.z = p0.z + rb.z + cx*w0.z + cy*w1.z + cz*w2.z;
  o4.w = p0.w + rb.w + cx*w0.w + cy*w1.w + cz*w2.w;
  *(float4*)(out + (size_t)row*CC + c) = o4;
}

extern "C" void kernel_launch(void* const* d_in, const int* in_sizes, int n_in,
                              void* d_out, int out_size, void* d_ws, size_t ws_size,
                              hipStream_t stream)
{
  (void)in_sizes; (void)n_in; (void)out_size; (void)ws_size;
  // d_in[0] is q (B,M,C): provably unused — attention softmax is uniform.
  const float* coarse = (const float*)d_in[1];
  const float* skel   = (const float*)d_in[2];
  const float* g1wr   = (const float*)d_in[3];
  const float* g1wl   = (const float*)d_in[4];
  const float* g1b    = (const float*)d_in[5];
  const float* g2wr   = (const float*)d_in[6];
  const float* g2wl   = (const float*)d_in[7];
  const float* g2b    = (const float*)d_in[8];
  const float* projw  = (const float*)d_in[9];
  const float* projb  = (const float*)d_in[10];
  const float* aiw    = (const float*)d_in[11];
  const float* aib    = (const float*)d_in[12];
  const float* aow    = (const float*)d_in[13];
  const float* aob    = (const float*)d_in[14];
  const float* i1w    = (const float*)d_in[15];
  const float* i1b    = (const float*)d_in[16];
  const float* bng    = (const float*)d_in[17];
  const float* bnb    = (const float*)d_in[18];
  const float* bnm    = (const float*)d_in[19];
  const float* bnv    = (const float*)d_in[20];
  const float* i2w    = (const float*)d_in[21];
  const float* i2b    = (const float*)d_in[22];
  const float* redw   = (const float*)d_in[23];
  const float* redb   = (const float*)d_in[24];
  float* out = (float*)d_out;

  char* ws = (char*)d_ws;
  int*   idx_ws = (int*)(ws + WS_IDX);
  float* h1_ws  = (float*)(ws + WS_H1);
  float* pmax   = (float*)(ws + WS_PMAX);
  float* q_ws   = (float*)(ws + WS_Q);
  float* y_ws   = (float*)(ws + WS_Y);
  float* g2_ws  = (float*)(ws + WS_G2);
  float* basep  = (float*)(ws + WS_BASEP);

  k_knn_gc1<<<4096, 256, 0, stream>>>(skel, g1wr, g1wl, g1b, idx_ws, h1_ws);
  k_gc2_max<<<512, 256, 0, stream>>>(h1_ws, idx_ws, g2wr, g2wl, g2b, pmax);
  k_mid<<<128, 256, 0, stream>>>(pmax, projw, projb, aiw, aib, aow, aob,
                                 i1w, i1b, bng, bnb, bnm, bnv, q_ws, y_ws);
  k_inc2<<<512, 256, 0, stream>>>(y_ws, i2w, i2b, g2_ws);
  k_base<<<dim3(32, 6), 256, 0, stream>>>(g2_ws, q_ws, redw, basep);
  k_out<<<5376, 256, 0, stream>>>(basep, redb, redw, coarse, out);
}

// Round 8
// 267.660 us; speedup vs baseline: 2.8022x; 1.0618x over previous
//
#include <hip/hip_runtime.h>

#define NB 32      // batches
#define MM 448
#define CC 384
#define SS 512
#define KNN 8

// workspace byte offsets
#define WS_IDX   0u
#define WS_H1    524288u                 // int idx[32][512][8] before this
#define WS_PMAX  (WS_H1 + 4194304u)      // float h1[32][512][64]
#define WS_Q     (WS_PMAX + 262144u)     // float pmax[512][128]
#define WS_Y     (WS_Q + 49152u)         // float y[32][1024]
#define WS_G2    (WS_Y + 131072u)        // float g2[32][1024]
#define WS_VV    WS_IDX                  // vv reuses idx region (dead after gc2)

// ------------------------------------------------- K1: KNN + gc1, wave-per-point
__global__ __launch_bounds__(256) void k_knn_gc1(
    const float* __restrict__ skel,
    const float* __restrict__ w1root, const float* __restrict__ w1rel,
    const float* __restrict__ b1,
    int* __restrict__ idx_ws, float* __restrict__ h1_ws)
{
  int b   = blockIdx.x >> 7;          // 128 groups of 4 points per batch
  int grp = blockIdx.x & 127;
  __shared__ __align__(16) float4 sk[SS];
  const float* sb = skel + b * SS * 3;
  for (int t = threadIdx.x; t < SS; t += 256)
    sk[t] = make_float4(sb[t*3+0], sb[t*3+1], sb[t*3+2], 0.f);
  __syncthreads();

  int wave = threadIdx.x >> 6, lane = threadIdx.x & 63;
  int i = grp * 4 + wave;             // this wave's point
  float4 pi = sk[i];

  float bd[KNN];
#pragma unroll
  for (int t = 0; t < KNN; t++) {
    int j = lane + (t << 6);
    float4 p = sk[j];
    float d2;
    {
      // match reference arithmetic exactly: (dx^2+dy^2)+dz^2, no fma contraction
#pragma clang fp contract(off)
      float dx = pi.x - p.x, dy = pi.y - p.y, dz = pi.z - p.z;
      d2 = (dx*dx + dy*dy) + dz*dz;
    }
    bd[t] = (j == i) ? 3e38f : d2;
  }

  int win[KNN];
  int* idx_base = idx_ws + (size_t)(b*SS + i) * KNN;
#pragma unroll
  for (int t = 0; t < KNN; t++) {
    float bestd = bd[0]; int bests = 0;
#pragma unroll
    for (int s = 1; s < KNN; s++)
      if (bd[s] < bestd) { bestd = bd[s]; bests = s; }
    int bestj = lane + (bests << 6);
#pragma unroll
    for (int m = 1; m < 64; m <<= 1) {
      float od = __shfl_xor(bestd, m, 64);
      int   oj = __shfl_xor(bestj, m, 64);
      if (od < bestd || (od == bestd && oj < bestj)) { bestd = od; bestj = oj; }
    }
    win[t] = bestj;
    if (lane == t) idx_base[t] = bestj;
    if ((bestj & 63) == lane) {
      int sl = bestj >> 6;
#pragma unroll
      for (int s = 0; s < KNN; s++) if (s == sl) bd[s] = 3e38f;
    }
  }

  float a0 = 0.f, a1 = 0.f, a2 = 0.f;
#pragma unroll
  for (int t = 0; t < KNN; t++) {
    float4 n = sk[win[t]];
    a0 += n.x; a1 += n.y; a2 += n.z;
  }

  int c = lane;
  float h = b1[c] + pi.x*w1root[c] + pi.y*w1root[64+c] + pi.z*w1root[128+c]
                  + a0*w1rel[c]   + a1*w1rel[64+c]   + a2*w1rel[128+c];
  h = fmaxf(h, 0.f);
  h1_ws[(size_t)(b*SS + i) * 64 + lane] = h;
}

// -------- K2: gc2+max as one GEMM [16384x128]@[128x128], fused agg-gather + max
__global__ __launch_bounds__(256) void k_gc2_max(
    const float* __restrict__ h1_ws, const int* __restrict__ idx_ws,
    const float* __restrict__ w2root, const float* __restrict__ w2rel,
    const float* __restrict__ b2, float* __restrict__ pmax)
{
  int b = blockIdx.x >> 4, chunk = blockIdx.x & 15;
  int r0 = chunk * 32;
  __shared__ __align__(16) float X[32*129];   // [row][k], stride 129
  __shared__ __align__(16) float Wt[32*128];  // k-chunk of stacked W
  __shared__ float mred[8*128];
  __shared__ int nbs[32*KNN];

  const float* h1b = h1_ws + (size_t)b * SS * 64;
  nbs[threadIdx.x] = idx_ws[(b*SS + r0)*KNN + threadIdx.x];   // 256 = 32*8
#pragma unroll
  for (int p = 0; p < 8; p++) {
    int idx = threadIdx.x + 256*p;
    int r = idx >> 6, k = idx & 63;
    X[r*129 + k] = h1b[(r0 + r)*64 + k];
  }
  __syncthreads();   // nbs ready
#pragma unroll
  for (int p = 0; p < 8; p++) {
    int idx = threadIdx.x + 256*p;
    int r = idx >> 6, k = idx & 63;
    const int* nb = nbs + r*KNN;
    float s = 0.f;
#pragma unroll
    for (int j = 0; j < KNN; j++) s += h1b[nb[j]*64 + k];
    X[r*129 + 64 + k] = s;
  }

  int rg = threadIdx.x >> 5, cg = threadIdx.x & 31;
  float acc[4][4];
#pragma unroll
  for (int r = 0; r < 4; r++)
#pragma unroll
    for (int u = 0; u < 4; u++) acc[r][u] = 0.f;

  const float* wsrc[4] = { w2root, w2root + 32*128, w2rel, w2rel + 32*128 };
#pragma unroll 1
  for (int ch = 0; ch < 4; ch++) {
    __syncthreads();
    const float* ws = wsrc[ch];
#pragma unroll
    for (int p = 0; p < 16; p++) {
      int idx = threadIdx.x + 256*p;
      Wt[idx] = ws[idx];                 // coalesced
    }
    __syncthreads();
    int kb = ch * 32;
    const float* xr0 = X + (rg*4+0)*129 + kb;
    const float* xr1 = X + (rg*4+1)*129 + kb;
    const float* xr2 = X + (rg*4+2)*129 + kb;
    const float* xr3 = X + (rg*4+3)*129 + kb;
#pragma unroll 4
    for (int k = 0; k < 32; k++) {
      float4 w4 = *(const float4*)(Wt + k*128 + cg*4);
      float x0 = xr0[k], x1 = xr1[k], x2 = xr2[k], x3 = xr3[k];
      acc[0][0] += x0*w4.x; acc[0][1] += x0*w4.y; acc[0][2] += x0*w4.z; acc[0][3] += x0*w4.w;
      acc[1][0] += x1*w4.x; acc[1][1] += x1*w4.y; acc[1][2] += x1*w4.z; acc[1][3] += x1*w4.w;
      acc[2][0] += x2*w4.x; acc[2][1] += x2*w4.y; acc[2][2] += x2*w4.z; acc[2][3] += x2*w4.w;
      acc[3][0] += x3*w4.x; acc[3][1] += x3*w4.y; acc[3][2] += x3*w4.z; acc[3][3] += x3*w4.w;
    }
  }
#pragma unroll
  for (int u = 0; u < 4; u++)
    mred[rg*128 + cg*4 + u] =
      fmaxf(fmaxf(acc[0][u], acc[1][u]), fmaxf(acc[2][u], acc[3][u]));
  __syncthreads();
  if (threadIdx.x < 128) {
    int col = threadIdx.x;
    float mx = mred[col];
#pragma unroll
    for (int g = 1; g < 8; g++) mx = fmaxf(mx, mred[g*128 + col]);
    pmax[(size_t)(b*16 + chunk)*128 + col] = mx + b2[col];
  }
}

// ---- K3: chainA = proxy-max + kv (redundant per block) + vv slice.
// 384 blocks (12/batch); vv dots are 8-lane-split + 3-shuffle reduce.
__global__ __launch_bounds__(256) void k_chainA(
    const float* __restrict__ pmax,
    const float* __restrict__ projw, const float* __restrict__ projb,
    const float* __restrict__ aiw, const float* __restrict__ aib,
    float* __restrict__ vv_ws)
{
  int b = blockIdx.x / 12, sl = blockIdx.x % 12;
  int t = threadIdx.x;
  __shared__ __align__(16) float proxy[128];
  __shared__ __align__(16) float kv[CC];
  if (t < 128) {
    float m = -3e38f;
    for (int ch = 0; ch < 16; ch++)
      m = fmaxf(m, pmax[(size_t)(b*16 + ch)*128 + t]);
    proxy[t] = m;
  }
  __syncthreads();
  for (int c = t; c < CC; c += 256) {        // kv redundant; projw L2-resident
    float acc = projb[c];
    for (int s = 0; s < 128; s++) acc += proxy[s] * projw[s*CC + c];
    kv[c] = acc;
  }
  __syncthreads();
  int o = sl*32 + (t >> 3), qq = t & 7;      // 32 vv outputs, 8 lanes each
  const float* wr = aiw + (size_t)(2*CC + o) * CC + qq*48;
  const float* xr = kv + qq*48;
  float acc = 0.f;
#pragma unroll
  for (int k = 0; k < 48; k += 4) {
    float4 w4 = *(const float4*)(wr + k);
    float4 x4 = *(const float4*)(xr + k);
    acc += w4.x*x4.x + w4.y*x4.y + w4.z*x4.z + w4.w*x4.w;
  }
  acc += __shfl_xor(acc, 1, 64);
  acc += __shfl_xor(acc, 2, 64);
  acc += __shfl_xor(acc, 4, 64);
  if (qq == 0) vv_ws[b*CC + o] = acc + aib[2*CC + o];
}

// ---- K4: chainB = qv (redundant, 4-lane-split) + q_ws + inc1+BN slice.
// 256 blocks (8/batch).
__global__ __launch_bounds__(256) void k_chainB(
    const float* __restrict__ vv_ws,
    const float* __restrict__ aow, const float* __restrict__ aob,
    const float* __restrict__ i1w, const float* __restrict__ i1b,
    const float* __restrict__ bng, const float* __restrict__ bnb,
    const float* __restrict__ bnm, const float* __restrict__ bnv,
    float* __restrict__ q_ws, float* __restrict__ y_ws)
{
  int b = blockIdx.x >> 3, sl = blockIdx.x & 7;
  int t = threadIdx.x;
  __shared__ __align__(16) float vv[CC];
  __shared__ __align__(16) float qv[CC];
  for (int i = t; i < CC; i += 256) vv[i] = vv_ws[b*CC + i];
  __syncthreads();
  {  // qv: 6 rounds x 64 outputs, 4 lanes each (96-elem sub-dots)
    int qq = t & 3;
    const float* xr = vv + qq*96;
#pragma unroll 1
    for (int r = 0; r < 6; r++) {
      int o = r*64 + (t >> 2);
      const float* wr = aow + (size_t)o * CC + qq*96;
      float acc = 0.f;
#pragma unroll
      for (int k = 0; k < 96; k += 4) {
        float4 w4 = *(const float4*)(wr + k);
        float4 x4 = *(const float4*)(xr + k);
        acc += w4.x*x4.x + w4.y*x4.y + w4.z*x4.z + w4.w*x4.w;
      }
      acc += __shfl_xor(acc, 1, 64);
      acc += __shfl_xor(acc, 2, 64);
      if (qq == 0) {
        float v = acc + aob[o];
        qv[o] = v;
        if (sl == 0) q_ws[b*CC + o] = v;
      }
    }
  }
  __syncthreads();
  {  // inc1 slice: 128 outputs, 2 lanes each (192-elem sub-dots)
    int o = sl*128 + (t >> 1), qq = t & 1;
    const float* wr = i1w + (size_t)o * CC + qq*192;
    const float* xr = qv + qq*192;
    float acc = 0.f;
#pragma unroll 12
    for (int k = 0; k < 192; k += 4) {
      float4 w4 = *(const float4*)(wr + k);
      float4 x4 = *(const float4*)(xr + k);
      acc += w4.x*x4.x + w4.y*x4.y + w4.z*x4.z + w4.w*x4.w;
    }
    acc += __shfl_xor(acc, 1, 64);
    if (qq == 0) {
      float a = acc + i1b[o];
      float z = bng[o] * (a - bnm[o]) * rsqrtf(bnv[o] + 1e-5f) + bnb[o];
      y_ws[b*1024 + o] = (z >= 0.f) ? z : 0.2f * z;
    }
  }
}

// ---------------- K5: inc2. 4 lanes per output, contiguous quarter-rows (K=1024).
__global__ __launch_bounds__(256) void k_inc2(
    const float* __restrict__ y_ws, const float* __restrict__ inc2_w,
    const float* __restrict__ inc2_b, float* __restrict__ g2_ws)
{
  int b = blockIdx.x >> 4, og = blockIdx.x & 15;
  int t = threadIdx.x;
  int o = og*64 + (t >> 2), qq = t & 3;
  __shared__ __align__(16) float xs[1024];
  for (int i = t; i < 1024; i += 256) xs[i] = y_ws[b*1024 + i];
  __syncthreads();
  const float* wr = inc2_w + (size_t)o * 1024 + qq*256;
  const float* xr = xs + qq*256;
  float acc = 0.f;
#pragma unroll 8
  for (int kk = 0; kk < 256; kk += 4) {
    float4 w4 = *(const float4*)(wr + kk);
    float4 x4 = *(const float4*)(xr + kk);
    acc += w4.x*x4.x + w4.y*x4.y + w4.z*x4.z + w4.w*x4.w;
  }
  acc += __shfl_xor(acc, 1, 64);
  acc += __shfl_xor(acc, 2, 64);
  if (qq == 0) g2_ws[b*1024 + o] = acc + inc2_b[o];
}

// ------ K6: base GEMM + fused output write.
// grid (32 b, 6 o-chunks of 64); 4 waves split K=1408, LDS reduce, then each
// block streams its 448x64 slice of out with the coarse rank-3 term.
__global__ __launch_bounds__(256) void k_base_out(
    const float* __restrict__ g2_ws, const float* __restrict__ q_ws,
    const float* __restrict__ red_w, const float* __restrict__ red_b,
    const float* __restrict__ coarse, float* __restrict__ out)
{
  int b = blockIdx.x;
  int o0 = blockIdx.y * 64;
  int wv = threadIdx.x >> 6, lane = threadIdx.x & 63;
  __shared__ __align__(16) float X[1408];
  __shared__ float part[4][64];
  __shared__ __align__(16) float baseS[64];
  for (int i = threadIdx.x; i < 1408; i += 256)
    X[i] = (i < 1024) ? g2_ws[b*1024 + i] : q_ws[b*CC + (i - 1024)];
  __syncthreads();
  int k0 = wv * 352;
  float acc = 0.f;
  const float* wbase = red_w + o0 + lane;
#pragma unroll 4
  for (int k = 0; k < 352; k++)
    acc += X[k0 + k] * wbase[(size_t)(k0 + k) * CC];
  part[wv][lane] = acc;
  __syncthreads();
  if (threadIdx.x < 64)
    baseS[lane] = part[0][lane] + part[1][lane] + part[2][lane] + part[3][lane]
                + red_b[o0 + lane];
  __syncthreads();
  int c4 = threadIdx.x & 15;           // 16 float4 cols
  int r0 = threadIdx.x >> 4;           // 16 row phases
  int c = o0 + c4*4;
  float4 base4 = *(const float4*)(baseS + c4*4);
  float4 w0 = *(const float4*)(red_w + (size_t)1408*CC + c);
  float4 w1 = *(const float4*)(red_w + (size_t)1409*CC + c);
  float4 w2 = *(const float4*)(red_w + (size_t)1410*CC + c);
#pragma unroll 4
  for (int m = r0; m < MM; m += 16) {
    const float* cr = coarse + (size_t)(b*MM + m) * 3;
    float cx = cr[0], cy = cr[1], cz = cr[2];
    float4 o4;
    o4.x = base4.x + cx*w0.x + cy*w1.x + cz*w2.x;
    o4.y = base4.y + cx*w0.y + cy*w1.y + cz*w2.y;
    o4.z = base4.z + cx*w0.z + cy*w1.z + cz*w2.z;
    o4.w = base4.w + cx*w0.w + cy*w1.w + cz*w2.w;
    *(float4*)(out + (size_t)(b*MM + m)*CC + c) = o4;
  }
}

extern "C" void kernel_launch(void* const* d_in, const int* in_sizes, int n_in,
                              void* d_out, int out_size, void* d_ws, size_t ws_size,
                              hipStream_t stream)
{
  (void)in_sizes; (void)n_in; (void)out_size; (void)ws_size;
  // d_in[0] is q (B,M,C): provably unused — attention softmax is uniform.
  const float* coarse = (const float*)d_in[1];
  const float* skel   = (const float*)d_in[2];
  const float* g1wr   = (const float*)d_in[3];
  const float* g1wl   = (const float*)d_in[4];
  const float* g1b    = (const float*)d_in[5];
  const float* g2wr   = (const float*)d_in[6];
  const float* g2wl   = (const float*)d_in[7];
  const float* g2b    = (const float*)d_in[8];
  const float* projw  = (const float*)d_in[9];
  const float* projb  = (const float*)d_in[10];
  const float* aiw    = (const float*)d_in[11];
  const float* aib    = (const float*)d_in[12];
  const float* aow    = (const float*)d_in[13];
  const float* aob    = (const float*)d_in[14];
  const float* i1w    = (const float*)d_in[15];
  const float* i1b    = (const float*)d_in[16];
  const float* bng    = (const float*)d_in[17];
  const float* bnb    = (const float*)d_in[18];
  const float* bnm    = (const float*)d_in[19];
  const float* bnv    = (const float*)d_in[20];
  const float* i2w    = (const float*)d_in[21];
  const float* i2b    = (const float*)d_in[22];
  const float* redw   = (const float*)d_in[23];
  const float* redb   = (const float*)d_in[24];
  float* out = (float*)d_out;

  char* ws = (char*)d_ws;
  int*   idx_ws = (int*)(ws + WS_IDX);
  float* h1_ws  = (float*)(ws + WS_H1);
  float* pmax   = (float*)(ws + WS_PMAX);
  float* q_ws   = (float*)(ws + WS_Q);
  float* y_ws   = (float*)(ws + WS_Y);
  float* g2_ws  = (float*)(ws + WS_G2);
  float* vv_ws  = (float*)(ws + WS_VV);   // reuses idx region (dead after gc2)

  k_knn_gc1<<<4096, 256, 0, stream>>>(skel, g1wr, g1wl, g1b, idx_ws, h1_ws);
  k_gc2_max<<<512, 256, 0, stream>>>(h1_ws, idx_ws, g2wr, g2wl, g2b, pmax);
  k_chainA<<<384, 256, 0, stream>>>(pmax, projw, projb, aiw, aib, vv_ws);
  k_chainB<<<256, 256, 0, stream>>>(vv_ws, aow, aob, i1w, i1b,
                                    bng, bnb, bnm, bnv, q_ws, y_ws);
  k_inc2<<<512, 256, 0, stream>>>(y_ws, i2w, i2b, g2_ws);
  k_base_out<<<dim3(32, 6), 256, 0, stream>>>(g2_ws, q_ws, redw, redb, coarse, out);
}

// Round 9
// 247.062 us; speedup vs baseline: 3.0358x; 1.0834x over previous
//
#include <hip/hip_runtime.h>

#define NB 32      // batches
#define MM 448
#define CC 384
#define SS 512
#define KNN 8

// workspace byte offsets
#define WS_IDX   0u
#define WS_H1    524288u                 // int idx[32][512][8] before this
#define WS_PMAX  (WS_H1 + 4194304u)      // float h1[32][512][64]
#define WS_Q     (WS_PMAX + 262144u)     // float pmax[512][128]
#define WS_Y     (WS_Q + 49152u)         // float y[32][1024]
#define WS_G2    (WS_Y + 131072u)        // float g2[32][1024]
#define WS_PP    WS_H1                   // pp[44][32][384] reuses h1 (dead after gc2)
#define WS_VV    WS_IDX                  // vv reuses idx region (dead after gc2)

// ------------------------------------------------- K1: KNN + gc1, wave-per-point
__global__ __launch_bounds__(256) void k_knn_gc1(
    const float* __restrict__ skel,
    const float* __restrict__ w1root, const float* __restrict__ w1rel,
    const float* __restrict__ b1,
    int* __restrict__ idx_ws, float* __restrict__ h1_ws)
{
  int b   = blockIdx.x >> 7;          // 128 groups of 4 points per batch
  int grp = blockIdx.x & 127;
  __shared__ __align__(16) float4 sk[SS];
  const float* sb = skel + b * SS * 3;
  for (int t = threadIdx.x; t < SS; t += 256)
    sk[t] = make_float4(sb[t*3+0], sb[t*3+1], sb[t*3+2], 0.f);
  __syncthreads();

  int wave = threadIdx.x >> 6, lane = threadIdx.x & 63;
  int i = grp * 4 + wave;             // this wave's point
  float4 pi = sk[i];

  float bd[KNN];
#pragma unroll
  for (int t = 0; t < KNN; t++) {
    int j = lane + (t << 6);
    float4 p = sk[j];
    float d2;
    {
      // match reference arithmetic exactly: (dx^2+dy^2)+dz^2, no fma contraction
#pragma clang fp contract(off)
      float dx = pi.x - p.x, dy = pi.y - p.y, dz = pi.z - p.z;
      d2 = (dx*dx + dy*dy) + dz*dz;
    }
    bd[t] = (j == i) ? 3e38f : d2;
  }

  int win[KNN];
  int* idx_base = idx_ws + (size_t)(b*SS + i) * KNN;
#pragma unroll
  for (int t = 0; t < KNN; t++) {
    float bestd = bd[0]; int bests = 0;
#pragma unroll
    for (int s = 1; s < KNN; s++)
      if (bd[s] < bestd) { bestd = bd[s]; bests = s; }
    int bestj = lane + (bests << 6);
#pragma unroll
    for (int m = 1; m < 64; m <<= 1) {
      float od = __shfl_xor(bestd, m, 64);
      int   oj = __shfl_xor(bestj, m, 64);
      if (od < bestd || (od == bestd && oj < bestj)) { bestd = od; bestj = oj; }
    }
    win[t] = bestj;
    if (lane == t) idx_base[t] = bestj;
    if ((bestj & 63) == lane) {
      int sl = bestj >> 6;
#pragma unroll
      for (int s = 0; s < KNN; s++) if (s == sl) bd[s] = 3e38f;
    }
  }

  float a0 = 0.f, a1 = 0.f, a2 = 0.f;
#pragma unroll
  for (int t = 0; t < KNN; t++) {
    float4 n = sk[win[t]];
    a0 += n.x; a1 += n.y; a2 += n.z;
  }

  int c = lane;
  float h = b1[c] + pi.x*w1root[c] + pi.y*w1root[64+c] + pi.z*w1root[128+c]
                  + a0*w1rel[c]   + a1*w1rel[64+c]   + a2*w1rel[128+c];
  h = fmaxf(h, 0.f);
  h1_ws[(size_t)(b*SS + i) * 64 + lane] = h;
}

// -------- K2: gc2+max as one GEMM [16384x128]@[128x128], fused agg-gather + max
__global__ __launch_bounds__(256) void k_gc2_max(
    const float* __restrict__ h1_ws, const int* __restrict__ idx_ws,
    const float* __restrict__ w2root, const float* __restrict__ w2rel,
    const float* __restrict__ b2, float* __restrict__ pmax)
{
  int b = blockIdx.x >> 4, chunk = blockIdx.x & 15;
  int r0 = chunk * 32;
  __shared__ __align__(16) float X[32*129];   // [row][k], stride 129
  __shared__ __align__(16) float Wt[32*128];  // k-chunk of stacked W
  __shared__ float mred[8*128];
  __shared__ int nbs[32*KNN];

  const float* h1b = h1_ws + (size_t)b * SS * 64;
  nbs[threadIdx.x] = idx_ws[(b*SS + r0)*KNN + threadIdx.x];   // 256 = 32*8
#pragma unroll
  for (int p = 0; p < 8; p++) {
    int idx = threadIdx.x + 256*p;
    int r = idx >> 6, k = idx & 63;
    X[r*129 + k] = h1b[(r0 + r)*64 + k];
  }
  __syncthreads();   // nbs ready
#pragma unroll
  for (int p = 0; p < 8; p++) {
    int idx = threadIdx.x + 256*p;
    int r = idx >> 6, k = idx & 63;
    const int* nb = nbs + r*KNN;
    float s = 0.f;
#pragma unroll
    for (int j = 0; j < KNN; j++) s += h1b[nb[j]*64 + k];
    X[r*129 + 64 + k] = s;
  }

  int rg = threadIdx.x >> 5, cg = threadIdx.x & 31;
  float acc[4][4];
#pragma unroll
  for (int r = 0; r < 4; r++)
#pragma unroll
    for (int u = 0; u < 4; u++) acc[r][u] = 0.f;

  const float* wsrc[4] = { w2root, w2root + 32*128, w2rel, w2rel + 32*128 };
#pragma unroll 1
  for (int ch = 0; ch < 4; ch++) {
    __syncthreads();
    const float* ws = wsrc[ch];
#pragma unroll
    for (int p = 0; p < 16; p++) {
      int idx = threadIdx.x + 256*p;
      Wt[idx] = ws[idx];                 // coalesced
    }
    __syncthreads();
    int kb = ch * 32;
    const float* xr0 = X + (rg*4+0)*129 + kb;
    const float* xr1 = X + (rg*4+1)*129 + kb;
    const float* xr2 = X + (rg*4+2)*129 + kb;
    const float* xr3 = X + (rg*4+3)*129 + kb;
#pragma unroll 4
    for (int k = 0; k < 32; k++) {
      float4 w4 = *(const float4*)(Wt + k*128 + cg*4);
      float x0 = xr0[k], x1 = xr1[k], x2 = xr2[k], x3 = xr3[k];
      acc[0][0] += x0*w4.x; acc[0][1] += x0*w4.y; acc[0][2] += x0*w4.z; acc[0][3] += x0*w4.w;
      acc[1][0] += x1*w4.x; acc[1][1] += x1*w4.y; acc[1][2] += x1*w4.z; acc[1][3] += x1*w4.w;
      acc[2][0] += x2*w4.x; acc[2][1] += x2*w4.y; acc[2][2] += x2*w4.z; acc[2][3] += x2*w4.w;
      acc[3][0] += x3*w4.x; acc[3][1] += x3*w4.y; acc[3][2] += x3*w4.z; acc[3][3] += x3*w4.w;
    }
  }
#pragma unroll
  for (int u = 0; u < 4; u++)
    mred[rg*128 + cg*4 + u] =
      fmaxf(fmaxf(acc[0][u], acc[1][u]), fmaxf(acc[2][u], acc[3][u]));
  __syncthreads();
  if (threadIdx.x < 128) {
    int col = threadIdx.x;
    float mx = mred[col];
#pragma unroll
    for (int g = 1; g < 8; g++) mx = fmaxf(mx, mred[g*128 + col]);
    pmax[(size_t)(b*16 + chunk)*128 + col] = mx + b2[col];
  }
}

// ---- K3: chainA = proxy-max + kv (redundant per block) + vv slice.
// 384 blocks (12/batch); vv dots are 8-lane-split + 3-shuffle reduce.
__global__ __launch_bounds__(256) void k_chainA(
    const float* __restrict__ pmax,
    const float* __restrict__ projw, const float* __restrict__ projb,
    const float* __restrict__ aiw, const float* __restrict__ aib,
    float* __restrict__ vv_ws)
{
  int b = blockIdx.x / 12, sl = blockIdx.x % 12;
  int t = threadIdx.x;
  __shared__ __align__(16) float proxy[128];
  __shared__ __align__(16) float kv[CC];
  if (t < 128) {
    float m = -3e38f;
    for (int ch = 0; ch < 16; ch++)
      m = fmaxf(m, pmax[(size_t)(b*16 + ch)*128 + t]);
    proxy[t] = m;
  }
  __syncthreads();
  for (int c = t; c < CC; c += 256) {        // kv redundant; projw L2-resident
    float acc = projb[c];
    for (int s = 0; s < 128; s++) acc += proxy[s] * projw[s*CC + c];
    kv[c] = acc;
  }
  __syncthreads();
  int o = sl*32 + (t >> 3), qq = t & 7;      // 32 vv outputs, 8 lanes each
  const float* wr = aiw + (size_t)(2*CC + o) * CC + qq*48;
  const float* xr = kv + qq*48;
  float acc = 0.f;
#pragma unroll
  for (int k = 0; k < 48; k += 4) {
    float4 w4 = *(const float4*)(wr + k);
    float4 x4 = *(const float4*)(xr + k);
    acc += w4.x*x4.x + w4.y*x4.y + w4.z*x4.z + w4.w*x4.w;
  }
  acc += __shfl_xor(acc, 1, 64);
  acc += __shfl_xor(acc, 2, 64);
  acc += __shfl_xor(acc, 4, 64);
  if (qq == 0) vv_ws[b*CC + o] = acc + aib[2*CC + o];
}

// ---- K4: chainB = qv (redundant, 4-lane-split) + q_ws + inc1+BN slice.
// 256 blocks (8/batch).
__global__ __launch_bounds__(256) void k_chainB(
    const float* __restrict__ vv_ws,
    const float* __restrict__ aow, const float* __restrict__ aob,
    const float* __restrict__ i1w, const float* __restrict__ i1b,
    const float* __restrict__ bng, const float* __restrict__ bnb,
    const float* __restrict__ bnm, const float* __restrict__ bnv,
    float* __restrict__ q_ws, float* __restrict__ y_ws)
{
  int b = blockIdx.x >> 3, sl = blockIdx.x & 7;
  int t = threadIdx.x;
  __shared__ __align__(16) float vv[CC];
  __shared__ __align__(16) float qv[CC];
  for (int i = t; i < CC; i += 256) vv[i] = vv_ws[b*CC + i];
  __syncthreads();
  {  // qv: 6 rounds x 64 outputs, 4 lanes each (96-elem sub-dots)
    int qq = t & 3;
    const float* xr = vv + qq*96;
#pragma unroll 1
    for (int r = 0; r < 6; r++) {
      int o = r*64 + (t >> 2);
      const float* wr = aow + (size_t)o * CC + qq*96;
      float acc = 0.f;
#pragma unroll
      for (int k = 0; k < 96; k += 4) {
        float4 w4 = *(const float4*)(wr + k);
        float4 x4 = *(const float4*)(xr + k);
        acc += w4.x*x4.x + w4.y*x4.y + w4.z*x4.z + w4.w*x4.w;
      }
      acc += __shfl_xor(acc, 1, 64);
      acc += __shfl_xor(acc, 2, 64);
      if (qq == 0) {
        float v = acc + aob[o];
        qv[o] = v;
        if (sl == 0) q_ws[b*CC + o] = v;
      }
    }
  }
  __syncthreads();
  {  // inc1 slice: 128 outputs, 2 lanes each (192-elem sub-dots)
    int o = sl*128 + (t >> 1), qq = t & 1;
    const float* wr = i1w + (size_t)o * CC + qq*192;
    const float* xr = qv + qq*192;
    float acc = 0.f;
#pragma unroll 12
    for (int k = 0; k < 192; k += 4) {
      float4 w4 = *(const float4*)(wr + k);
      float4 x4 = *(const float4*)(xr + k);
      acc += w4.x*x4.x + w4.y*x4.y + w4.z*x4.z + w4.w*x4.w;
    }
    acc += __shfl_xor(acc, 1, 64);
    if (qq == 0) {
      float a = acc + i1b[o];
      float z = bng[o] * (a - bnm[o]) * rsqrtf(bnv[o] + 1e-5f) + bnb[o];
      y_ws[b*1024 + o] = (z >= 0.f) ? z : 0.2f * z;
    }
  }
}

// ---------------- K5: inc2. 4 lanes per output, contiguous quarter-rows (K=1024).
__global__ __launch_bounds__(256) void k_inc2(
    const float* __restrict__ y_ws, const float* __restrict__ inc2_w,
    const float* __restrict__ inc2_b, float* __restrict__ g2_ws)
{
  int b = blockIdx.x >> 4, og = blockIdx.x & 15;
  int t = threadIdx.x;
  int o = og*64 + (t >> 2), qq = t & 3;
  __shared__ __align__(16) float xs[1024];
  for (int i = t; i < 1024; i += 256) xs[i] = y_ws[b*1024 + i];
  __syncthreads();
  const float* wr = inc2_w + (size_t)o * 1024 + qq*256;
  const float* xr = xs + qq*256;
  float acc = 0.f;
#pragma unroll 8
  for (int kk = 0; kk < 256; kk += 4) {
    float4 w4 = *(const float4*)(wr + kk);
    float4 x4 = *(const float4*)(xr + kk);
    acc += w4.x*x4.x + w4.y*x4.y + w4.z*x4.z + w4.w*x4.w;
  }
  acc += __shfl_xor(acc, 1, 64);
  acc += __shfl_xor(acc, 2, 64);
  if (qq == 0) g2_ws[b*1024 + o] = acc + inc2_b[o];
}

// ------------- K6: base partial GEMM: pp[cg][b][o] = x[b][c0:c0+32] @ W[c0:c0+32]
// grid (44 c-chunks, 6 col-chunks of 64); W read exactly once across the grid
__global__ __launch_bounds__(256) void k_basep(
    const float* __restrict__ g2_ws, const float* __restrict__ q_ws,
    const float* __restrict__ red_w, float* __restrict__ pp)
{
  int cg = blockIdx.x;          // 0..43 (c0 = cg*32; <1024 -> g2, else q)
  int o0 = blockIdx.y * 64;     // 0..5
  int c0 = cg * 32;
  __shared__ __align__(16) float xs[32*33];   // [c][b] padded
  __shared__ __align__(16) float wt[32*64];   // [c][o]
#pragma unroll
  for (int p = 0; p < 8; p++) {
    int idx = threadIdx.x + 256*p;
    int c = idx >> 6, o = idx & 63;
    wt[idx] = red_w[(size_t)(c0 + c)*CC + o0 + o];
  }
  {
    int b = threadIdx.x >> 3, cp = threadIdx.x & 7;
    const float* src = (cg < 32) ? (g2_ws + b*1024 + c0)
                                 : (q_ws  + b*CC   + (c0 - 1024));
    float4 v = *(const float4*)(src + cp*4);
    xs[(cp*4+0)*33 + b] = v.x;
    xs[(cp*4+1)*33 + b] = v.y;
    xs[(cp*4+2)*33 + b] = v.z;
    xs[(cp*4+3)*33 + b] = v.w;
  }
  __syncthreads();
  int b = threadIdx.x >> 3, og = threadIdx.x & 7;
  float acc[8];
#pragma unroll
  for (int u = 0; u < 8; u++) acc[u] = 0.f;
#pragma unroll 8
  for (int c = 0; c < 32; c++) {
    float xv = xs[c*33 + b];
    float4 w0 = *(const float4*)(wt + c*64 + og*8);
    float4 w1 = *(const float4*)(wt + c*64 + og*8 + 4);
    acc[0] += xv*w0.x; acc[1] += xv*w0.y; acc[2] += xv*w0.z; acc[3] += xv*w0.w;
    acc[4] += xv*w1.x; acc[5] += xv*w1.y; acc[6] += xv*w1.z; acc[7] += xv*w1.w;
  }
  float* dst = pp + (size_t)(cg*32 + b)*CC + o0 + og*8;
  *(float4*)dst       = make_float4(acc[0], acc[1], acc[2], acc[3]);
  *(float4*)(dst + 4) = make_float4(acc[4], acc[5], acc[6], acc[7]);
}

// ------ K7: out2 = reduce pp in-LDS + write 32-row slice with coarse rank-3 term.
// grid (32 b, 14 m-chunks of 32 rows) = 448 blocks.
__global__ __launch_bounds__(256) void k_out2(
    const float* __restrict__ pp, const float* __restrict__ red_b,
    const float* __restrict__ red_w, const float* __restrict__ coarse,
    float* __restrict__ out)
{
  int b = blockIdx.x, mc = blockIdx.y;
  int t = threadIdx.x;
  __shared__ __align__(16) float baseS[CC];
  __shared__ __align__(16) float w3[3*CC];
  __shared__ float crs[32*4];
  // base[c] = red_b[c] + sum_cg pp[cg][b][c]   (pp is L2-resident, coalesced)
  for (int c = t; c < CC; c += 256) {
    float s = red_b[c];
#pragma unroll 4
    for (int cg = 0; cg < 44; cg++) s += pp[(size_t)cg*12288 + b*CC + c];
    baseS[c] = s;
  }
  for (int i = t; i < 3*CC; i += 256) w3[i] = red_w[(size_t)1408*CC + i];
  if (t < 96) {
    int r = t / 3, j = t % 3;
    crs[r*4 + j] = coarse[(size_t)(b*MM + mc*32 + r)*3 + j];
  }
  __syncthreads();
  int m0 = mc * 32;
#pragma unroll 4
  for (int p = 0; p < 12; p++) {
    int idx = t + 256*p;              // < 3072 = 32 rows * 96 float4
    int r = idx / 96, c4 = idx % 96;
    int c = c4 * 4;
    float4 b4 = *(const float4*)(baseS + c);
    float4 w0 = *(const float4*)(w3 + c);
    float4 w1 = *(const float4*)(w3 + CC + c);
    float4 w2 = *(const float4*)(w3 + 2*CC + c);
    float cx = crs[r*4+0], cy = crs[r*4+1], cz = crs[r*4+2];
    float4 o4;
    o4.x = b4.x + cx*w0.x + cy*w1.x + cz*w2.x;
    o4.y = b4.y + cx*w0.y + cy*w1.y + cz*w2.y;
    o4.z = b4.z + cx*w0.z + cy*w1.z + cz*w2.z;
    o4.w = b4.w + cx*w0.w + cy*w1.w + cz*w2.w;
    *(float4*)(out + (size_t)(b*MM + m0 + r)*CC + c) = o4;
  }
}

extern "C" void kernel_launch(void* const* d_in, const int* in_sizes, int n_in,
                              void* d_out, int out_size, void* d_ws, size_t ws_size,
                              hipStream_t stream)
{
  (void)in_sizes; (void)n_in; (void)out_size; (void)ws_size;
  // d_in[0] is q (B,M,C): provably unused — attention softmax is uniform.
  const float* coarse = (const float*)d_in[1];
  const float* skel   = (const float*)d_in[2];
  const float* g1wr   = (const float*)d_in[3];
  const float* g1wl   = (const float*)d_in[4];
  const float* g1b    = (const float*)d_in[5];
  const float* g2wr   = (const float*)d_in[6];
  const float* g2wl   = (const float*)d_in[7];
  const float* g2b    = (const float*)d_in[8];
  const float* projw  = (const float*)d_in[9];
  const float* projb  = (const float*)d_in[10];
  const float* aiw    = (const float*)d_in[11];
  const float* aib    = (const float*)d_in[12];
  const float* aow    = (const float*)d_in[13];
  const float* aob    = (const float*)d_in[14];
  const float* i1w    = (const float*)d_in[15];
  const float* i1b    = (const float*)d_in[16];
  const float* bng    = (const float*)d_in[17];
  const float* bnb    = (const float*)d_in[18];
  const float* bnm    = (const float*)d_in[19];
  const float* bnv    = (const float*)d_in[20];
  const float* i2w    = (const float*)d_in[21];
  const float* i2b    = (const float*)d_in[22];
  const float* redw   = (const float*)d_in[23];
  const float* redb   = (const float*)d_in[24];
  float* out = (float*)d_out;

  char* ws = (char*)d_ws;
  int*   idx_ws = (int*)(ws + WS_IDX);
  float* h1_ws  = (float*)(ws + WS_H1);
  float* pmax   = (float*)(ws + WS_PMAX);
  float* q_ws   = (float*)(ws + WS_Q);
  float* y_ws   = (float*)(ws + WS_Y);
  float* g2_ws  = (float*)(ws + WS_G2);
  float* pp     = (float*)(ws + WS_PP);   // reuses h1 region (dead after gc2)
  float* vv_ws  = (float*)(ws + WS_VV);   // reuses idx region (dead after gc2)

  k_knn_gc1<<<4096, 256, 0, stream>>>(skel, g1wr, g1wl, g1b, idx_ws, h1_ws);
  k_gc2_max<<<512, 256, 0, stream>>>(h1_ws, idx_ws, g2wr, g2wl, g2b, pmax);
  k_chainA<<<384, 256, 0, stream>>>(pmax, projw, projb, aiw, aib, vv_ws);
  k_chainB<<<256, 256, 0, stream>>>(vv_ws, aow, aob, i1w, i1b,
                                    bng, bnb, bnm, bnv, q_ws, y_ws);
  k_inc2<<<512, 256, 0, stream>>>(y_ws, i2w, i2b, g2_ws);
  k_basep<<<dim3(44, 6), 256, 0, stream>>>(g2_ws, q_ws, redw, pp);
  k_out2<<<dim3(32, 14), 256, 0, stream>>>(pp, redb, redw, coarse, out);
}

// Round 10
// 235.323 us; speedup vs baseline: 3.1872x; 1.0499x over previous
//
#include <hip/hip_runtime.h>

#define NB 32      // batches
#define MM 448
#define CC 384
#define SS 512
#define KNN 8

// workspace byte offsets
#define WS_IDX   0u
#define WS_H1    524288u                 // int idx[32][512][8] before this
#define WS_PMAX  (WS_H1 + 4194304u)      // float h1[32][512][64]
#define WS_Q     (WS_PMAX + 262144u)     // float pmax[512][128]
#define WS_Y     (WS_Q + 49152u)         // float y[32][1024]
#define WS_PP    WS_H1                   // pp[44][32][384] reuses h1 (dead after gc2)
#define WS_VV    WS_IDX                  // vv reuses idx region (dead after gc2)
#define WS_G2P   8388608u                // float g2p[16][32][1024] = 2 MB

// ------------------------------------------------- K1: KNN + gc1, wave-per-point
__global__ __launch_bounds__(256) void k_knn_gc1(
    const float* __restrict__ skel,
    const float* __restrict__ w1root, const float* __restrict__ w1rel,
    const float* __restrict__ b1,
    int* __restrict__ idx_ws, float* __restrict__ h1_ws)
{
  int b   = blockIdx.x >> 7;          // 128 groups of 4 points per batch
  int grp = blockIdx.x & 127;
  __shared__ __align__(16) float4 sk[SS];
  const float* sb = skel + b * SS * 3;
  for (int t = threadIdx.x; t < SS; t += 256)
    sk[t] = make_float4(sb[t*3+0], sb[t*3+1], sb[t*3+2], 0.f);
  __syncthreads();

  int wave = threadIdx.x >> 6, lane = threadIdx.x & 63;
  int i = grp * 4 + wave;             // this wave's point
  float4 pi = sk[i];

  float bd[KNN];
#pragma unroll
  for (int t = 0; t < KNN; t++) {
    int j = lane + (t << 6);
    float4 p = sk[j];
    float d2;
    {
      // match reference arithmetic exactly: (dx^2+dy^2)+dz^2, no fma contraction
#pragma clang fp contract(off)
      float dx = pi.x - p.x, dy = pi.y - p.y, dz = pi.z - p.z;
      d2 = (dx*dx + dy*dy) + dz*dz;
    }
    bd[t] = (j == i) ? 3e38f : d2;
  }

  int win[KNN];
  int* idx_base = idx_ws + (size_t)(b*SS + i) * KNN;
#pragma unroll
  for (int t = 0; t < KNN; t++) {
    float bestd = bd[0]; int bests = 0;
#pragma unroll
    for (int s = 1; s < KNN; s++)
      if (bd[s] < bestd) { bestd = bd[s]; bests = s; }
    int bestj = lane + (bests << 6);
#pragma unroll
    for (int m = 1; m < 64; m <<= 1) {
      float od = __shfl_xor(bestd, m, 64);
      int   oj = __shfl_xor(bestj, m, 64);
      if (od < bestd || (od == bestd && oj < bestj)) { bestd = od; bestj = oj; }
    }
    win[t] = bestj;
    if (lane == t) idx_base[t] = bestj;
    if ((bestj & 63) == lane) {
      int sl = bestj >> 6;
#pragma unroll
      for (int s = 0; s < KNN; s++) if (s == sl) bd[s] = 3e38f;
    }
  }

  float a0 = 0.f, a1 = 0.f, a2 = 0.f;
#pragma unroll
  for (int t = 0; t < KNN; t++) {
    float4 n = sk[win[t]];
    a0 += n.x; a1 += n.y; a2 += n.z;
  }

  int c = lane;
  float h = b1[c] + pi.x*w1root[c] + pi.y*w1root[64+c] + pi.z*w1root[128+c]
                  + a0*w1rel[c]   + a1*w1rel[64+c]   + a2*w1rel[128+c];
  h = fmaxf(h, 0.f);
  h1_ws[(size_t)(b*SS + i) * 64 + lane] = h;
}

// -------- K2: gc2+max as one GEMM [16384x128]@[128x128], fused agg-gather + max
__global__ __launch_bounds__(256) void k_gc2_max(
    const float* __restrict__ h1_ws, const int* __restrict__ idx_ws,
    const float* __restrict__ w2root, const float* __restrict__ w2rel,
    const float* __restrict__ b2, float* __restrict__ pmax)
{
  int b = blockIdx.x >> 4, chunk = blockIdx.x & 15;
  int r0 = chunk * 32;
  __shared__ __align__(16) float X[32*129];   // [row][k], stride 129
  __shared__ __align__(16) float Wt[32*128];  // k-chunk of stacked W
  __shared__ float mred[8*128];
  __shared__ int nbs[32*KNN];

  const float* h1b = h1_ws + (size_t)b * SS * 64;
  nbs[threadIdx.x] = idx_ws[(b*SS + r0)*KNN + threadIdx.x];   // 256 = 32*8
#pragma unroll
  for (int p = 0; p < 8; p++) {
    int idx = threadIdx.x + 256*p;
    int r = idx >> 6, k = idx & 63;
    X[r*129 + k] = h1b[(r0 + r)*64 + k];
  }
  __syncthreads();   // nbs ready
#pragma unroll
  for (int p = 0; p < 8; p++) {
    int idx = threadIdx.x + 256*p;
    int r = idx >> 6, k = idx & 63;
    const int* nb = nbs + r*KNN;
    float s = 0.f;
#pragma unroll
    for (int j = 0; j < KNN; j++) s += h1b[nb[j]*64 + k];
    X[r*129 + 64 + k] = s;
  }

  int rg = threadIdx.x >> 5, cg = threadIdx.x & 31;
  float acc[4][4];
#pragma unroll
  for (int r = 0; r < 4; r++)
#pragma unroll
    for (int u = 0; u < 4; u++) acc[r][u] = 0.f;

  const float* wsrc[4] = { w2root, w2root + 32*128, w2rel, w2rel + 32*128 };
#pragma unroll 1
  for (int ch = 0; ch < 4; ch++) {
    __syncthreads();
    const float* ws = wsrc[ch];
#pragma unroll
    for (int p = 0; p < 16; p++) {
      int idx = threadIdx.x + 256*p;
      Wt[idx] = ws[idx];                 // coalesced
    }
    __syncthreads();
    int kb = ch * 32;
    const float* xr0 = X + (rg*4+0)*129 + kb;
    const float* xr1 = X + (rg*4+1)*129 + kb;
    const float* xr2 = X + (rg*4+2)*129 + kb;
    const float* xr3 = X + (rg*4+3)*129 + kb;
#pragma unroll 4
    for (int k = 0; k < 32; k++) {
      float4 w4 = *(const float4*)(Wt + k*128 + cg*4);
      float x0 = xr0[k], x1 = xr1[k], x2 = xr2[k], x3 = xr3[k];
      acc[0][0] += x0*w4.x; acc[0][1] += x0*w4.y; acc[0][2] += x0*w4.z; acc[0][3] += x0*w4.w;
      acc[1][0] += x1*w4.x; acc[1][1] += x1*w4.y; acc[1][2] += x1*w4.z; acc[1][3] += x1*w4.w;
      acc[2][0] += x2*w4.x; acc[2][1] += x2*w4.y; acc[2][2] += x2*w4.z; acc[2][3] += x2*w4.w;
      acc[3][0] += x3*w4.x; acc[3][1] += x3*w4.y; acc[3][2] += x3*w4.z; acc[3][3] += x3*w4.w;
    }
  }
#pragma unroll
  for (int u = 0; u < 4; u++)
    mred[rg*128 + cg*4 + u] =
      fmaxf(fmaxf(acc[0][u], acc[1][u]), fmaxf(acc[2][u], acc[3][u]));
  __syncthreads();
  if (threadIdx.x < 128) {
    int col = threadIdx.x;
    float mx = mred[col];
#pragma unroll
    for (int g = 1; g < 8; g++) mx = fmaxf(mx, mred[g*128 + col]);
    pmax[(size_t)(b*16 + chunk)*128 + col] = mx + b2[col];
  }
}

// ---- K3: chainA = proxy-max + kv (redundant per block) + vv slice.
// 384 blocks (12/batch); vv dots are 8-lane-split + 3-shuffle reduce.
__global__ __launch_bounds__(256) void k_chainA(
    const float* __restrict__ pmax,
    const float* __restrict__ projw, const float* __restrict__ projb,
    const float* __restrict__ aiw, const float* __restrict__ aib,
    float* __restrict__ vv_ws)
{
  int b = blockIdx.x / 12, sl = blockIdx.x % 12;
  int t = threadIdx.x;
  __shared__ __align__(16) float proxy[128];
  __shared__ __align__(16) float kv[CC];
  if (t < 128) {
    float m = -3e38f;
    for (int ch = 0; ch < 16; ch++)
      m = fmaxf(m, pmax[(size_t)(b*16 + ch)*128 + t]);
    proxy[t] = m;
  }
  __syncthreads();
  for (int c = t; c < CC; c += 256) {        // kv redundant; projw L2-resident
    float acc = projb[c];
    for (int s = 0; s < 128; s++) acc += proxy[s] * projw[s*CC + c];
    kv[c] = acc;
  }
  __syncthreads();
  int o = sl*32 + (t >> 3), qq = t & 7;      // 32 vv outputs, 8 lanes each
  const float* wr = aiw + (size_t)(2*CC + o) * CC + qq*48;
  const float* xr = kv + qq*48;
  float acc = 0.f;
#pragma unroll
  for (int k = 0; k < 48; k += 4) {
    float4 w4 = *(const float4*)(wr + k);
    float4 x4 = *(const float4*)(xr + k);
    acc += w4.x*x4.x + w4.y*x4.y + w4.z*x4.z + w4.w*x4.w;
  }
  acc += __shfl_xor(acc, 1, 64);
  acc += __shfl_xor(acc, 2, 64);
  acc += __shfl_xor(acc, 4, 64);
  if (qq == 0) vv_ws[b*CC + o] = acc + aib[2*CC + o];
}

// ---- K4: chainB = qv (redundant, 4-lane-split) + q_ws + inc1+BN slice.
// 256 blocks (8/batch).
__global__ __launch_bounds__(256) void k_chainB(
    const float* __restrict__ vv_ws,
    const float* __restrict__ aow, const float* __restrict__ aob,
    const float* __restrict__ i1w, const float* __restrict__ i1b,
    const float* __restrict__ bng, const float* __restrict__ bnb,
    const float* __restrict__ bnm, const float* __restrict__ bnv,
    float* __restrict__ q_ws, float* __restrict__ y_ws)
{
  int b = blockIdx.x >> 3, sl = blockIdx.x & 7;
  int t = threadIdx.x;
  __shared__ __align__(16) float vv[CC];
  __shared__ __align__(16) float qv[CC];
  for (int i = t; i < CC; i += 256) vv[i] = vv_ws[b*CC + i];
  __syncthreads();
  {  // qv: 6 rounds x 64 outputs, 4 lanes each (96-elem sub-dots)
    int qq = t & 3;
    const float* xr = vv + qq*96;
#pragma unroll 1
    for (int r = 0; r < 6; r++) {
      int o = r*64 + (t >> 2);
      const float* wr = aow + (size_t)o * CC + qq*96;
      float acc = 0.f;
#pragma unroll
      for (int k = 0; k < 96; k += 4) {
        float4 w4 = *(const float4*)(wr + k);
        float4 x4 = *(const float4*)(xr + k);
        acc += w4.x*x4.x + w4.y*x4.y + w4.z*x4.z + w4.w*x4.w;
      }
      acc += __shfl_xor(acc, 1, 64);
      acc += __shfl_xor(acc, 2, 64);
      if (qq == 0) {
        float v = acc + aob[o];
        qv[o] = v;
        if (sl == 0) q_ws[b*CC + o] = v;
      }
    }
  }
  __syncthreads();
  {  // inc1 slice: 128 outputs, 2 lanes each (192-elem sub-dots)
    int o = sl*128 + (t >> 1), qq = t & 1;
    const float* wr = i1w + (size_t)o * CC + qq*192;
    const float* xr = qv + qq*192;
    float acc = 0.f;
#pragma unroll 12
    for (int k = 0; k < 192; k += 4) {
      float4 w4 = *(const float4*)(wr + k);
      float4 x4 = *(const float4*)(xr + k);
      acc += w4.x*x4.x + w4.y*x4.y + w4.z*x4.z + w4.w*x4.w;
    }
    acc += __shfl_xor(acc, 1, 64);
    if (qq == 0) {
      float a = acc + i1b[o];
      float z = bng[o] * (a - bnm[o]) * rsqrtf(bnv[o] + 1e-5f) + bnb[o];
      y_ws[b*1024 + o] = (z >= 0.f) ? z : 0.2f * z;
    }
  }
}

// ---- K5: inc2 as batched split-K GEMM [32x1024]@[1024x1024]^T.
// grid (16 kc, 16 oc) = 256 blocks; i2w read EXACTLY ONCE across the grid
// (was once per batch = 128 MB HBM). Partials g2p[kc][32][1024]; bias+reduce
// folded into k_basep's staging.
__global__ __launch_bounds__(256) void k_inc2(
    const float* __restrict__ y_ws, const float* __restrict__ i2w,
    float* __restrict__ g2p)
{
  int kc = blockIdx.x, oc = blockIdx.y;
  int t = threadIdx.x;
  __shared__ __align__(16) float ys[32*64];    // [b][k]
  __shared__ __align__(16) float wt[64*65];    // [k][o] padded (+1 bank rotate)
  // stage y slice: 2048 elements
#pragma unroll
  for (int p = 0; p < 8; p++) {
    int idx = t + 256*p;
    int b = idx >> 6, k = idx & 63;
    ys[idx] = y_ws[b*1024 + kc*64 + k];
  }
  // stage w tile transposed: 4096 elements, read coalesced in k, write stride-65
#pragma unroll
  for (int p = 0; p < 16; p++) {
    int idx = t + 256*p;
    int o = idx >> 6, k = idx & 63;
    wt[k*65 + o] = i2w[(size_t)(oc*64 + o)*1024 + kc*64 + k];
  }
  __syncthreads();
  int b = t >> 3, og = t & 7;          // thread: 1 batch x 8 outputs
  float acc[8];
#pragma unroll
  for (int u = 0; u < 8; u++) acc[u] = 0.f;
  const float* yb = ys + b*64;
#pragma unroll 4
  for (int k = 0; k < 64; k++) {
    float yv = yb[k];
    float4 w0 = *(const float4*)(wt + k*65 + og*8);
    float4 w1 = *(const float4*)(wt + k*65 + og*8 + 4);
    acc[0] += yv*w0.x; acc[1] += yv*w0.y; acc[2] += yv*w0.z; acc[3] += yv*w0.w;
    acc[4] += yv*w1.x; acc[5] += yv*w1.y; acc[6] += yv*w1.z; acc[7] += yv*w1.w;
  }
  float* dst = g2p + (size_t)(kc*32 + b)*1024 + oc*64 + og*8;
  *(float4*)dst       = make_float4(acc[0], acc[1], acc[2], acc[3]);
  *(float4*)(dst + 4) = make_float4(acc[4], acc[5], acc[6], acc[7]);
}

// ------------- K6: base partial GEMM: pp[cg][b][o] = x[b][c0:c0+32] @ W[c0:c0+32]
// grid (44 c-chunks, 6 col-chunks of 64); W read exactly once across the grid.
// For cg<32, x is the 16-way reduction of g2p (+ i2b bias).
__global__ __launch_bounds__(256) void k_basep(
    const float* __restrict__ g2p, const float* __restrict__ i2b,
    const float* __restrict__ q_ws,
    const float* __restrict__ red_w, float* __restrict__ pp)
{
  int cg = blockIdx.x;          // 0..43 (c0 = cg*32; <1024 -> g2 path, else q)
  int o0 = blockIdx.y * 64;     // 0..5
  int c0 = cg * 32;
  __shared__ __align__(16) float xs[32*33];   // [c][b] padded
  __shared__ __align__(16) float wt[32*64];   // [c][o]
#pragma unroll
  for (int p = 0; p < 8; p++) {
    int idx = threadIdx.x + 256*p;
    int c = idx >> 6, o = idx & 63;
    wt[idx] = red_w[(size_t)(c0 + c)*CC + o0 + o];
  }
  {
    int b = threadIdx.x >> 3, cp = threadIdx.x & 7;
    if (cg < 32) {
      // reduce 16 k-partials + bias for 4 consecutive c's
      float4 s;
      const float* pb = g2p + b*1024 + c0 + cp*4;
      s.x = i2b[c0+cp*4+0]; s.y = i2b[c0+cp*4+1];
      s.z = i2b[c0+cp*4+2]; s.w = i2b[c0+cp*4+3];
#pragma unroll 4
      for (int kp = 0; kp < 16; kp++) {
        float4 v = *(const float4*)(pb + (size_t)kp*32768);
        s.x += v.x; s.y += v.y; s.z += v.z; s.w += v.w;
      }
      xs[(cp*4+0)*33 + b] = s.x;
      xs[(cp*4+1)*33 + b] = s.y;
      xs[(cp*4+2)*33 + b] = s.z;
      xs[(cp*4+3)*33 + b] = s.w;
    } else {
      float4 v = *(const float4*)(q_ws + b*CC + (c0 - 1024) + cp*4);
      xs[(cp*4+0)*33 + b] = v.x;
      xs[(cp*4+1)*33 + b] = v.y;
      xs[(cp*4+2)*33 + b] = v.z;
      xs[(cp*4+3)*33 + b] = v.w;
    }
  }
  __syncthreads();
  int b = threadIdx.x >> 3, og = threadIdx.x & 7;
  float acc[8];
#pragma unroll
  for (int u = 0; u < 8; u++) acc[u] = 0.f;
#pragma unroll 8
  for (int c = 0; c < 32; c++) {
    float xv = xs[c*33 + b];
    float4 w0 = *(const float4*)(wt + c*64 + og*8);
    float4 w1 = *(const float4*)(wt + c*64 + og*8 + 4);
    acc[0] += xv*w0.x; acc[1] += xv*w0.y; acc[2] += xv*w0.z; acc[3] += xv*w0.w;
    acc[4] += xv*w1.x; acc[5] += xv*w1.y; acc[6] += xv*w1.z; acc[7] += xv*w1.w;
  }
  float* dst = pp + (size_t)(cg*32 + b)*CC + o0 + og*8;
  *(float4*)dst       = make_float4(acc[0], acc[1], acc[2], acc[3]);
  *(float4*)(dst + 4) = make_float4(acc[4], acc[5], acc[6], acc[7]);
}

// ------ K7: out2 = reduce pp in-LDS + write 32-row slice with coarse rank-3 term.
// grid (32 b, 14 m-chunks of 32 rows) = 448 blocks.
__global__ __launch_bounds__(256) void k_out2(
    const float* __restrict__ pp, const float* __restrict__ red_b,
    const float* __restrict__ red_w, const float* __restrict__ coarse,
    float* __restrict__ out)
{
  int b = blockIdx.x, mc = blockIdx.y;
  int t = threadIdx.x;
  __shared__ __align__(16) float baseS[CC];
  __shared__ __align__(16) float w3[3*CC];
  __shared__ float crs[32*4];
  for (int c = t; c < CC; c += 256) {
    float s = red_b[c];
#pragma unroll 4
    for (int cg = 0; cg < 44; cg++) s += pp[(size_t)cg*12288 + b*CC + c];
    baseS[c] = s;
  }
  for (int i = t; i < 3*CC; i += 256) w3[i] = red_w[(size_t)1408*CC + i];
  if (t < 96) {
    int r = t / 3, j = t % 3;
    crs[r*4 + j] = coarse[(size_t)(b*MM + mc*32 + r)*3 + j];
  }
  __syncthreads();
  int m0 = mc * 32;
#pragma unroll 4
  for (int p = 0; p < 12; p++) {
    int idx = t + 256*p;              // < 3072 = 32 rows * 96 float4
    int r = idx / 96, c4 = idx % 96;
    int c = c4 * 4;
    float4 b4 = *(const float4*)(baseS + c);
    float4 w0 = *(const float4*)(w3 + c);
    float4 w1 = *(const float4*)(w3 + CC + c);
    float4 w2 = *(const float4*)(w3 + 2*CC + c);
    float cx = crs[r*4+0], cy = crs[r*4+1], cz = crs[r*4+2];
    float4 o4;
    o4.x = b4.x + cx*w0.x + cy*w1.x + cz*w2.x;
    o4.y = b4.y + cx*w0.y + cy*w1.y + cz*w2.y;
    o4.z = b4.z + cx*w0.z + cy*w1.z + cz*w2.z;
    o4.w = b4.w + cx*w0.w + cy*w1.w + cz*w2.w;
    *(float4*)(out + (size_t)(b*MM + m0 + r)*CC + c) = o4;
  }
}

extern "C" void kernel_launch(void* const* d_in, const int* in_sizes, int n_in,
                              void* d_out, int out_size, void* d_ws, size_t ws_size,
                              hipStream_t stream)
{
  (void)in_sizes; (void)n_in; (void)out_size; (void)ws_size;
  // d_in[0] is q (B,M,C): provably unused — attention softmax is uniform.
  const float* coarse = (const float*)d_in[1];
  const float* skel   = (const float*)d_in[2];
  const float* g1wr   = (const float*)d_in[3];
  const float* g1wl   = (const float*)d_in[4];
  const float* g1b    = (const float*)d_in[5];
  const float* g2wr   = (const float*)d_in[6];
  const float* g2wl   = (const float*)d_in[7];
  const float* g2b    = (const float*)d_in[8];
  const float* projw  = (const float*)d_in[9];
  const float* projb  = (const float*)d_in[10];
  const float* aiw    = (const float*)d_in[11];
  const float* aib    = (const float*)d_in[12];
  const float* aow    = (const float*)d_in[13];
  const float* aob    = (const float*)d_in[14];
  const float* i1w    = (const float*)d_in[15];
  const float* i1b    = (const float*)d_in[16];
  const float* bng    = (const float*)d_in[17];
  const float* bnb    = (const float*)d_in[18];
  const float* bnm    = (const float*)d_in[19];
  const float* bnv    = (const float*)d_in[20];
  const float* i2w    = (const float*)d_in[21];
  const float* i2b    = (const float*)d_in[22];
  const float* redw   = (const float*)d_in[23];
  const float* redb   = (const float*)d_in[24];
  float* out = (float*)d_out;

  char* ws = (char*)d_ws;
  int*   idx_ws = (int*)(ws + WS_IDX);
  float* h1_ws  = (float*)(ws + WS_H1);
  float* pmax   = (float*)(ws + WS_PMAX);
  float* q_ws   = (float*)(ws + WS_Q);
  float* y_ws   = (float*)(ws + WS_Y);
  float* pp     = (float*)(ws + WS_PP);   // reuses h1 region (dead after gc2)
  float* vv_ws  = (float*)(ws + WS_VV);   // reuses idx region (dead after gc2)
  float* g2p    = (float*)(ws + WS_G2P);  // 2 MB at 8 MB offset

  k_knn_gc1<<<4096, 256, 0, stream>>>(skel, g1wr, g1wl, g1b, idx_ws, h1_ws);
  k_gc2_max<<<512, 256, 0, stream>>>(h1_ws, idx_ws, g2wr, g2wl, g2b, pmax);
  k_chainA<<<384, 256, 0, stream>>>(pmax, projw, projb, aiw, aib, vv_ws);
  k_chainB<<<256, 256, 0, stream>>>(vv_ws, aow, aob, i1w, i1b,
                                    bng, bnb, bnm, bnv, q_ws, y_ws);
  k_inc2<<<dim3(16, 16), 256, 0, stream>>>(y_ws, i2w, g2p);
  k_basep<<<dim3(44, 6), 256, 0, stream>>>(g2p, i2b, q_ws, redw, pp);
  k_out2<<<dim3(32, 14), 256, 0, stream>>>(pp, redb, redw, coarse, out);
}